// Round 14
// baseline (596.093 us; speedup 1.0000x reference)
//
#include <hip/hip_runtime.h>
#include <hip/hip_bf16.h>
#include <cstddef>

// Problem constants
#define NB 64      // batch
#define LL 128     // L1 == L2
#define EE 300     // embed dim
#define DD 256     // hidden dim
#define NLAYERS 10
#define MROWS (NB * LL)  // 8192

static constexpr float BN_SC = 0.9995003746877562f;  // 1/sqrt(1+1e-3)

typedef unsigned short u16;
typedef __attribute__((ext_vector_type(4))) unsigned short us4;
typedef __attribute__((ext_vector_type(8))) unsigned short us8;
typedef __attribute__((ext_vector_type(8))) short bfrag;   // 8 bf16 (4 VGPR)
typedef __attribute__((ext_vector_type(4))) float f4;      // MFMA C/D

#define MFMA_B16(a, b, c) __builtin_amdgcn_mfma_f32_16x16x32_bf16(a, b, c, 0, 0, 0)

__device__ __forceinline__ u16 f2bf(float x) {
  union { float f; unsigned u; } v; v.f = x;
  unsigned r = v.u + 0x7FFFu + ((v.u >> 16) & 1u);  // RNE
  return (u16)(r >> 16);
}
__device__ __forceinline__ float bf2f(u16 s) {
  union { unsigned u; float f; } v; v.u = (unsigned)s << 16;
  return v.f;
}
__device__ __forceinline__ float4 ld4(const float* p) { return *(const float4*)p; }

// ---------------- async global->LDS staging (16B/lane) -------------------
__device__ __forceinline__ void async16(void* lds, const void* g) {
  __builtin_amdgcn_global_load_lds(
      (const __attribute__((address_space(1))) unsigned int*)g,
      (__attribute__((address_space(3))) unsigned int*)lds, 16, 0, 0);
}

// ===== BK=64 tiles, XOR-swizzled (byte ^= (row&7)<<4) ====================
// LDS is written LINEARLY by global_load_lds; the swizzle is realized by
// pre-swizzling the per-lane GLOBAL source part (both-sides-or-neither).
__device__ __forceinline__ int swz64(int row, int colbyte) {
  return (row * 128 + colbyte) ^ ((row & 7) << 4);
}
__device__ __forceinline__ bfrag ldsT(const u16* T, int row, int colbyte) {
  return *(const bfrag*)((const char*)T + swz64(row, colbyte));
}

// [128 rows][64 k] (16KB): 4 async16/thread, source part pre-swizzled.
__device__ __forceinline__ void stage128x64(const u16* __restrict__ src, int ld,
                                            int r0, int k0, u16* lds, int t) {
  const int w = t >> 6;
#pragma unroll
  for (int j = 0; j < 4; ++j) {
    const int c = j * 256 + t;         // chunk 0..1023
    const int row = c >> 3, part = c & 7;
    const int sp = part ^ (row & 7);
    async16((char*)lds + j * 4096 + w * 1024,
            src + (size_t)(r0 + row) * ld + k0 + sp * 8);
  }
}
// [64 rows][64 k] (8KB): 2 async16/thread.
__device__ __forceinline__ void stage64x64(const u16* __restrict__ src, int ld,
                                           int r0, int k0, u16* lds, int t) {
  const int w = t >> 6;
#pragma unroll
  for (int j = 0; j < 2; ++j) {
    const int c = j * 256 + t;         // chunk 0..511
    const int row = c >> 3, part = c & 7;
    const int sp = part ^ (row & 7);
    async16((char*)lds + j * 4096 + w * 1024,
            src + (size_t)(r0 + row) * ld + k0 + sp * 8);
  }
}

// 128m x 64n over K=64 (2 MFMA sub-steps): swizzled reads.
__device__ __forceinline__ void step_k64(const u16* As, const u16* Bs, int wm,
                                         int wn, int fr, int fq, f4 acc[4][2]) {
#pragma unroll
  for (int ks2 = 0; ks2 < 2; ++ks2) {
    bfrag a[4], b[2];
#pragma unroll
    for (int i = 0; i < 4; ++i)
      a[i] = ldsT(As, wm * 64 + i * 16 + fr, ks2 * 64 + fq * 16);
#pragma unroll
    for (int j = 0; j < 2; ++j)
      b[j] = ldsT(Bs, wn * 32 + j * 16 + fr, ks2 * 64 + fq * 16);
#pragma unroll
    for (int i = 0; i < 4; ++i)
#pragma unroll
      for (int j = 0; j < 2; ++j) acc[i][j] = MFMA_B16(a[i], b[j], acc[i][j]);
  }
}

__device__ __forceinline__ void step2_k64(const u16* As, const u16* B2s,
                                          const u16* Bgs, int wm, int wn,
                                          int fr, int fq, f4 accv[4][2],
                                          f4 accg[4][2]) {
#pragma unroll
  for (int ks2 = 0; ks2 < 2; ++ks2) {
    bfrag a[4], b2[2], bg[2];
#pragma unroll
    for (int i = 0; i < 4; ++i)
      a[i] = ldsT(As, wm * 64 + i * 16 + fr, ks2 * 64 + fq * 16);
#pragma unroll
    for (int j = 0; j < 2; ++j) {
      b2[j] = ldsT(B2s, wn * 32 + j * 16 + fr, ks2 * 64 + fq * 16);
      bg[j] = ldsT(Bgs, wn * 32 + j * 16 + fr, ks2 * 64 + fq * 16);
    }
#pragma unroll
    for (int i = 0; i < 4; ++i)
#pragma unroll
      for (int j = 0; j < 2; ++j) {
        accv[i][j] = MFMA_B16(a[i], b2[j], accv[i][j]);
        accg[i][j] = MFMA_B16(a[i], bg[j], accg[i][j]);
      }
  }
}

// direct MFMA fragment load from row-major [row][k] bf16 global (L2-hot)
__device__ __forceinline__ bfrag gfrag(const u16* __restrict__ p, int ld, int row, int k) {
  return *(const bfrag*)(p + (size_t)row * ld + k);
}

// swizzled byte offset into a [128][128] bf16 LDS matrix (conflict-free b128 reads)
__device__ __forceinline__ int eswz(int row, int colbyte) {
  return (row * 256 + colbyte) ^ ((row & 7) << 4);
}
__device__ __forceinline__ bfrag ldsE(const u16* E, int row, int colbyte) {
  return *(const bfrag*)((const char*)E + eswz(row, colbyte));
}

// ---------------- fused prologue: weight transposes + gather + VP pad ----
__device__ void txw_tile(const float* __restrict__ src, u16* __restrict__ dst,
                         int K, int N, int Kpad, int k0, int n0, int t,
                         float (*tileS)[65]) {
  __syncthreads();  // protect LDS across task iterations
  {
    const int kr = t >> 2, nc = (t & 3) * 16;
    const int k = k0 + kr;
#pragma unroll
    for (int j = 0; j < 16; j += 4) {
      float4 v = (k < K) ? ld4(src + (size_t)k * N + n0 + nc + j)
                         : make_float4(0.f, 0.f, 0.f, 0.f);
      tileS[kr][nc + j + 0] = v.x; tileS[kr][nc + j + 1] = v.y;
      tileS[kr][nc + j + 2] = v.z; tileS[kr][nc + j + 3] = v.w;
    }
  }
  __syncthreads();
  {
    const int nr = t >> 2, kc = (t & 3) * 16;
    us8 o0, o1;
#pragma unroll
    for (int j = 0; j < 8; ++j) {
      o0[j] = f2bf(tileS[kc + j][nr]);
      o1[j] = f2bf(tileS[kc + 8 + j][nr]);
    }
    u16* d = dst + (size_t)(n0 + nr) * Kpad + k0 + kc;
    *(us8*)d = o0;
    *(us8*)(d + 8) = o1;
  }
}

__global__ __launch_bounds__(256)
void k_prep(const float* __restrict__ W1f, const float* __restrict__ W1r,
            const float* __restrict__ W2, const float* __restrict__ Wg,
            const float* __restrict__ Wf1, const float* __restrict__ Wf2,
            u16* __restrict__ Wt1f, u16* __restrict__ Wt1r,
            u16* __restrict__ Wt2, u16* __restrict__ Wtg,
            u16* __restrict__ Wf1t, u16* __restrict__ Wf2t,
            const float* __restrict__ embed, const int* __restrict__ ids1,
            const int* __restrict__ ids2, u16* __restrict__ X1,
            u16* __restrict__ X2, u16* __restrict__ VPh, u16* __restrict__ VPl) {
  __shared__ float tileS[64][65];
  const int t = threadIdx.x;
  const int blk = blockIdx.x, nblk = gridDim.x;
  for (int it = blk; it < 20; it += nblk)
    txw_tile(W1f, Wt1f, 300, 256, 320, (it % 5) * 64, (it / 5) * 64, t, tileS);
  for (int it = blk; it < 144; it += nblk) {
    const int l = it / 16, r = it % 16;
    txw_tile(W1r + (size_t)l * 65536, Wt1r + (size_t)l * 65536, 256, 256, 256,
             (r % 4) * 64, (r / 4) * 64, t, tileS);
  }
  for (int it = blk; it < 320; it += nblk) {
    const int l = it / 32, r = it % 32;
    txw_tile(W2 + (size_t)l * 131072, Wt2 + (size_t)l * 131072, 512, 256, 512,
             (r % 8) * 64, (r / 8) * 64, t, tileS);
  }
  for (int it = blk; it < 160; it += nblk) {
    const int l = it / 16, r = it % 16;
    txw_tile(Wg + (size_t)l * 65536, Wtg + (size_t)l * 65536, 256, 256, 256,
             (r % 4) * 64, (r / 4) * 64, t, tileS);
  }
  for (int it = blk; it < 256; it += nblk)
    txw_tile(Wf1, Wf1t, 1024, 1024, 1024, (it % 16) * 64, (it / 16) * 64, t, tileS);
  for (int it = blk; it < 256; it += nblk)
    txw_tile(Wf2, Wf2t, 1024, 1024, 1024, (it % 16) * 64, (it / 16) * 64, t, tileS);
  for (int g = blk; g < 4096; g += nblk) {
    const int side = g & 1;
    const int* ids = side ? ids2 : ids1;
    u16* E = side ? X2 : X1;
    const int row = (g >> 1) * 4 + (t >> 6);
    const int lane = t & 63;
    const float* src = embed + (size_t)ids[row] * EE;
    u16* dst = E + (size_t)row * 320;
#pragma unroll
    for (int j = 0; j < 5; ++j) {
      const int c = lane + 64 * j;
      dst[c] = f2bf(c < EE ? src[c] : 0.f);
    }
  }
  // zero the MLP pad rows 64..127 of VPh/VPl
  for (int it = blk; it < 128; it += nblk) {
    const int arr = it & 1, row = 64 + (it >> 1);
    u16* dst = (arr ? VPl : VPh) + (size_t)row * 1024;
#pragma unroll
    for (int j = 0; j < 4; ++j) dst[t * 4 + j] = 0;
  }
}

// --- LBR-1 n64 BK=64 swizzled, depth-2 counted-vmcnt pipeline (T4) -------
__global__ __launch_bounds__(256, 2)
void mfma_lbr(const u16* __restrict__ A0, const u16* __restrict__ A1, int lda,
              int K, const u16* __restrict__ Wt, const float* __restrict__ bias,
              const float* __restrict__ gam, const float* __restrict__ bet,
              u16* __restrict__ O0, u16* __restrict__ O1,
              u16* __restrict__ HTa, u16* __restrict__ HTb,
              float* __restrict__ SQPa, float* __restrict__ SQPb) {
  const int side = blockIdx.z;
  const u16* A = side ? A1 : A0;
  u16* O = side ? O1 : O0;
  u16* HT = side ? HTb : HTa;
  float* SQP = side ? SQPb : SQPa;
  __shared__ u16 As[3][128 * 64], Bs[3][64 * 64];  // 48KB + 24KB
  const int t = threadIdx.x;
  const int m0 = blockIdx.x * 128, n0 = blockIdx.y * 64;
  const int lane = t & 63, w = t >> 6, wm = w >> 1, wn = w & 1;
  const int fr = lane & 15, fq = lane >> 4;
  f4 acc[4][2] = {};
  const int nt = K / 64;  // 4 (K=256) or 5 (K=320)
  // prologue: stages 0 and 1 in flight (6 loads each per thread)
  stage128x64(A, lda, m0, 0, As[0], t);
  stage64x64(Wt, K, n0, 0, Bs[0], t);
  stage128x64(A, lda, m0, 64, As[1], t);
  stage64x64(Wt, K, n0, 64, Bs[1], t);
  for (int ks = 0; ks < nt; ++ks) {
    // wait for stage(ks) only; stage(ks+1)'s 6 loads stay in flight
    if (ks < nt - 1) asm volatile("s_waitcnt vmcnt(6)" ::: "memory");
    else             asm volatile("s_waitcnt vmcnt(0)" ::: "memory");
    __builtin_amdgcn_sched_barrier(0);
    __builtin_amdgcn_s_barrier();
    if (ks + 2 < nt) {
      stage128x64(A, lda, m0, (ks + 2) * 64, As[(ks + 2) % 3], t);
      stage64x64(Wt, K, n0, (ks + 2) * 64, Bs[(ks + 2) % 3], t);
    }
    step_k64(As[ks % 3], Bs[ks % 3], wm, wn, fr, fq, acc);
  }
  const int b = m0 >> 7;
  float rsq[4][4] = {};
#pragma unroll
  for (int nj = 0; nj < 2; ++nj) {
    const int n = n0 + wn * 32 + nj * 16 + fr;
    const float sc = gam[n] * BN_SC, bi = bias[n], be = bet[n];
#pragma unroll
    for (int mi = 0; mi < 4; ++mi) {
      const int m = m0 + wm * 64 + mi * 16 + fq * 4;
      us4 pk;
#pragma unroll
      for (int r = 0; r < 4; ++r) {
        const float x = sc * (acc[mi][nj][r] + bi) + be;
        const u16 hb = f2bf(fmaxf(x, 0.f));
        O[(size_t)(m + r) * DD + n] = hb;
        pk[r] = hb;
        const float h = bf2f(hb);  // norms must match stored bf16 H
        rsq[mi][r] += h * h;
      }
      *(us4*)&HT[((size_t)b * DD + n) * LL + (m & 127)] = pk;
    }
  }
#pragma unroll
  for (int mi = 0; mi < 4; ++mi)
#pragma unroll
    for (int r = 0; r < 4; ++r) {
      float v = rsq[mi][r];
      v += __shfl_xor(v, 1, 64); v += __shfl_xor(v, 2, 64);
      v += __shfl_xor(v, 4, 64); v += __shfl_xor(v, 8, 64);
      rsq[mi][r] = v;
    }
  if (fr == 0) {
    const int p = blockIdx.y * 2 + wn;  // 8 partials per row
#pragma unroll
    for (int mi = 0; mi < 4; ++mi)
#pragma unroll
      for (int r = 0; r < 4; ++r)
        SQP[(size_t)p * MROWS + m0 + wm * 64 + mi * 16 + fq * 4 + r] = rsq[mi][r];
  }
}

// ------- fused att+attn per (batch, N-half, side): E in LDS, PV out ------
__global__ __launch_bounds__(256, 2)
void attf(const u16* __restrict__ H1, const u16* __restrict__ H2,
          const float* __restrict__ SQP1, const float* __restrict__ SQP2,
          const u16* __restrict__ HT1, const u16* __restrict__ HT2,
          u16* __restrict__ BETA, u16* __restrict__ ALPHA) {
  const int b = blockIdx.x, nh = blockIdx.y, side = blockIdx.z;
  __shared__ u16 Elds[128 * 128];  // 32KB swizzled (Ê or Ê^T per side)
  __shared__ float sqs[2][128], rowp[2][128], colp[2][128];
  const int t = threadIdx.x, lane = t & 63, w = t >> 6;
  const int wm = w >> 1, wn = w & 1;
  const int fr = lane & 15, fq = lane >> 4;
  const int r0 = b * LL;
  if (t < 128) {
    float s = 0.f;
#pragma unroll
    for (int p = 0; p < 8; ++p) s += SQP1[(size_t)p * MROWS + r0 + t];
    sqs[0][t] = s;
  } else {
    const int u = t - 128;
    float s = 0.f;
#pragma unroll
    for (int p = 0; p < 8; ++p) s += SQP2[(size_t)p * MROWS + r0 + u];
    sqs[1][u] = s;
  }
  // QK^T: full 128x128 E, no-LDS frag loads
  f4 acc[4][4] = {};
#pragma unroll
  for (int ks = 0; ks < 8; ++ks) {
    bfrag a[4], bv[4];
#pragma unroll
    for (int mi = 0; mi < 4; ++mi)
      a[mi] = gfrag(H1, DD, r0 + wm * 64 + mi * 16 + fr, ks * 32 + fq * 8);
#pragma unroll
    for (int nj = 0; nj < 4; ++nj)
      bv[nj] = gfrag(H2, DD, r0 + wn * 64 + nj * 16 + fr, ks * 32 + fq * 8);
#pragma unroll
    for (int mi = 0; mi < 4; ++mi)
#pragma unroll
      for (int nj = 0; nj < 4; ++nj) acc[mi][nj] = MFMA_B16(a[mi], bv[nj], acc[mi][nj]);
  }
  __syncthreads();  // sqs visible
  float rp[4][4] = {}, cp[4] = {};
#pragma unroll
  for (int nj = 0; nj < 4; ++nj) {
    const int n = wn * 64 + nj * 16 + fr;
    const float s2 = sqs[1][n];
#pragma unroll
    for (int mi = 0; mi < 4; ++mi) {
      const int m = wm * 64 + mi * 16 + fq * 4;
#pragma unroll
      for (int r = 0; r < 4; ++r) {
        const float d = sqs[0][m + r] + s2 - 2.f * acc[mi][nj][r];
        const float e = __expf(1.f / (1.f + d));
        acc[mi][nj][r] = e;
        rp[mi][r] += e;
        cp[nj] += e;
      }
    }
  }
#pragma unroll
  for (int mi = 0; mi < 4; ++mi)
#pragma unroll
    for (int r = 0; r < 4; ++r) {
      float v = rp[mi][r];
      v += __shfl_xor(v, 1, 64); v += __shfl_xor(v, 2, 64);
      v += __shfl_xor(v, 4, 64); v += __shfl_xor(v, 8, 64);
      rp[mi][r] = v;
    }
#pragma unroll
  for (int nj = 0; nj < 4; ++nj) {
    float v = cp[nj];
    v += __shfl_xor(v, 16, 64); v += __shfl_xor(v, 32, 64);
    cp[nj] = v;
  }
  if (fr == 0)
#pragma unroll
    for (int mi = 0; mi < 4; ++mi)
#pragma unroll
      for (int r = 0; r < 4; ++r)
        rowp[wn][wm * 64 + mi * 16 + fq * 4 + r] = rp[mi][r];
  if (fq == 0)
#pragma unroll
    for (int nj = 0; nj < 4; ++nj)
      colp[wm][wn * 64 + nj * 16 + fr] = cp[nj];
  __syncthreads();
  if (side == 0) {  // row-normalized Ê
#pragma unroll
    for (int nj = 0; nj < 4; ++nj) {
      const int n = wn * 64 + nj * 16 + fr;
#pragma unroll
      for (int mi = 0; mi < 4; ++mi) {
        const int m = wm * 64 + mi * 16 + fq * 4;
#pragma unroll
        for (int r = 0; r < 4; ++r) {
          const float riv = 1.f / (rowp[0][m + r] + rowp[1][m + r]);
          *(u16*)((char*)Elds + eswz(m + r, n * 2)) = f2bf(acc[mi][nj][r] * riv);
        }
      }
    }
  } else {  // col-normalized Ê^T
#pragma unroll
    for (int nj = 0; nj < 4; ++nj) {
      const int n = wn * 64 + nj * 16 + fr;
      const float civ = 1.f / (colp[0][n] + colp[1][n]);
#pragma unroll
      for (int mi = 0; mi < 4; ++mi) {
        const int m = wm * 64 + mi * 16 + fq * 4;
        us4 pk;
#pragma unroll
        for (int r = 0; r < 4; ++r) pk[r] = f2bf(acc[mi][nj][r] * civ);
        *(us4*)((char*)Elds + eswz(n, m * 2)) = pk;
      }
    }
  }
  __syncthreads();
  // PV: O = Ê @ H (B-frags from HT rows = H columns), this block's 128-col half
  const u16* HT = side ? HT1 : HT2;
  f4 pv[4][4] = {};
#pragma unroll
  for (int ks = 0; ks < 4; ++ks) {
    bfrag a[4], bv[4];
#pragma unroll
    for (int mi = 0; mi < 4; ++mi)
      a[mi] = ldsE(Elds, wm * 64 + mi * 16 + fr, ks * 64 + fq * 16);
#pragma unroll
    for (int nj = 0; nj < 4; ++nj)
      bv[nj] = gfrag(HT, LL, b * DD + nh * 128 + wn * 64 + nj * 16 + fr, ks * 32 + fq * 8);
#pragma unroll
    for (int mi = 0; mi < 4; ++mi)
#pragma unroll
      for (int nj = 0; nj < 4; ++nj) pv[mi][nj] = MFMA_B16(a[mi], bv[nj], pv[mi][nj]);
  }
  u16* O = side ? ALPHA : BETA;
#pragma unroll
  for (int nj = 0; nj < 4; ++nj) {
    const int n = nh * 128 + wn * 64 + nj * 16 + fr;
#pragma unroll
    for (int mi = 0; mi < 4; ++mi) {
      const int m = wm * 64 + mi * 16 + fq * 4;
#pragma unroll
      for (int r = 0; r < 4; ++r)
        O[(size_t)(r0 + m + r) * DD + n] = f2bf(pv[mi][nj][r]);
    }
  }
}

// --- vg n64 BK=64 swizzled: W2 || Wg + gate update (+pool on last) -------
__global__ __launch_bounds__(256, 2)
void mfma_vg(const u16* __restrict__ Hbf1, const u16* __restrict__ Hbf2,
             const u16* __restrict__ BETA, const u16* __restrict__ ALPHA,
             const u16* __restrict__ Wt2, const u16* __restrict__ Wtg,
             const float* __restrict__ b2, const float* __restrict__ g2,
             const float* __restrict__ be2, const float* __restrict__ bgv,
             u16* __restrict__ X0, u16* __restrict__ X1p, int dopool,
             u16* __restrict__ VPh, u16* __restrict__ VPl) {
  const int side = blockIdx.z;
  const u16* H = side ? Hbf2 : Hbf1;
  const u16* CC = side ? ALPHA : BETA;
  u16* X = side ? X1p : X0;
  const int m0 = blockIdx.x * 128, n0 = blockIdx.y * 64;
  __shared__ u16 As[2][128 * 64], B2s[2][64 * 64], Bgs[2][64 * 64];  // 64KB
  __shared__ float pmx[2][64], psm[2][64];
  const int t = threadIdx.x;
  const int lane = t & 63, w = t >> 6, wm = w >> 1, wn = w & 1;
  const int fr = lane & 15, fq = lane >> 4;
  f4 accv[4][2] = {}, accg[4][2] = {};
  stage128x64(H, DD, m0, 0, As[0], t);
  stage64x64(Wt2, 2 * DD, n0, 0, B2s[0], t);
  stage64x64(Wtg, DD, n0, 0, Bgs[0], t);
  __syncthreads();
  for (int ks = 0; ks < 8; ++ks) {
    const int cur = ks & 1;
    if (ks + 1 < 8) {
      const u16* Asrc = (ks + 1 < 4) ? H : CC;
      stage128x64(Asrc, DD, m0, ((ks + 1) & 3) * 64, As[cur ^ 1], t);
      stage64x64(Wt2, 2 * DD, n0, (ks + 1) * 64, B2s[cur ^ 1], t);
      if (ks + 1 < 4) stage64x64(Wtg, DD, n0, (ks + 1) * 64, Bgs[cur ^ 1], t);
    }
    if (ks < 4)
      step2_k64(As[cur], B2s[cur], Bgs[cur], wm, wn, fr, fq, accv, accg);
    else
      step_k64(As[cur], B2s[cur], wm, wn, fr, fq, accv);
    __syncthreads();
  }
  float pmax[2] = {-1e30f, -1e30f}, psum[2] = {0.f, 0.f};
#pragma unroll
  for (int nj = 0; nj < 2; ++nj) {
    const int n = n0 + wn * 32 + nj * 16 + fr;
    const float sc = g2[n] * BN_SC, bi = b2[n], be = be2[n], bgn = bgv[n];
#pragma unroll
    for (int mi = 0; mi < 4; ++mi) {
      const int m = m0 + wm * 64 + mi * 16 + fq * 4;
#pragma unroll
      for (int r = 0; r < 4; ++r) {
        const float v = fmaxf(sc * (accv[mi][nj][r] + bi) + be, 0.f);
        const float g = 1.f / (1.f + __expf(-(accg[mi][nj][r] + bgn)));
        const float h = bf2f(H[(size_t)(m + r) * DD + n]);
        const u16 xb = f2bf(v * g + h * (1.f - g));
        X[(size_t)(m + r) * DD + n] = xb;
        if (dopool) {
          const float xv = bf2f(xb);
          pmax[nj] = fmaxf(pmax[nj], xv);
          psum[nj] += xv;
        }
      }
    }
  }
  if (dopool) {
#pragma unroll
    for (int nj = 0; nj < 2; ++nj) {
      float mx = pmax[nj], sm = psum[nj];
      mx = fmaxf(mx, __shfl_xor(mx, 16, 64)); sm += __shfl_xor(sm, 16, 64);
      mx = fmaxf(mx, __shfl_xor(mx, 32, 64)); sm += __shfl_xor(sm, 32, 64);
      if (fq == 0) {
        pmx[wm][wn * 32 + nj * 16 + fr] = mx;
        psm[wm][wn * 32 + nj * 16 + fr] = sm;
      }
    }
    __syncthreads();
    if (t < 64) {
      const float mx = fmaxf(pmx[0][t], pmx[1][t]);
      const float sm = psm[0][t] + psm[1][t];
      const int b = m0 >> 7;
      const int col = n0 + t;
      const u16 mh = f2bf(mx);
      VPh[(size_t)b * 1024 + side * 256 + col] = mh;
      VPl[(size_t)b * 1024 + side * 256 + col] = f2bf(mx - bf2f(mh));
      const u16 sh = f2bf(sm);
      VPh[(size_t)b * 1024 + (2 + side) * 256 + col] = sh;
      VPl[(size_t)b * 1024 + (2 + side) * 256 + col] = f2bf(sm - bf2f(sh));
    }
  }
}

// ------- MLP full-K no-LDS (8 blocks): O = relu((Ah+Al)@Wt + b) ----------
__global__ __launch_bounds__(256, 2)
void mlp_full(const u16* __restrict__ Ah, const u16* __restrict__ Al,
              const u16* __restrict__ Wt, const float* __restrict__ bias,
              u16* __restrict__ Oh, u16* __restrict__ Ol,
              float* __restrict__ Of) {
  const int n0 = blockIdx.x * 128;
  const int t = threadIdx.x, lane = t & 63, w = t >> 6;
  const int wm = w >> 1, wn = w & 1;
  const int fr = lane & 15, fq = lane >> 4;
  f4 acc[4][4] = {};
#pragma unroll 4
  for (int ks = 0; ks < 32; ++ks) {
    bfrag ah[4], al[4], bv[4];
#pragma unroll
    for (int mi = 0; mi < 4; ++mi) {
      ah[mi] = gfrag(Ah, 1024, wm * 64 + mi * 16 + fr, ks * 32 + fq * 8);
      al[mi] = gfrag(Al, 1024, wm * 64 + mi * 16 + fr, ks * 32 + fq * 8);
    }
#pragma unroll
    for (int nj = 0; nj < 4; ++nj)
      bv[nj] = gfrag(Wt, 1024, n0 + wn * 64 + nj * 16 + fr, ks * 32 + fq * 8);
#pragma unroll
    for (int mi = 0; mi < 4; ++mi)
#pragma unroll
      for (int nj = 0; nj < 4; ++nj) {
        acc[mi][nj] = MFMA_B16(ah[mi], bv[nj], acc[mi][nj]);
        acc[mi][nj] = MFMA_B16(al[mi], bv[nj], acc[mi][nj]);
      }
  }
#pragma unroll
  for (int nj = 0; nj < 4; ++nj) {
    const int n = n0 + wn * 64 + nj * 16 + fr;
    const float bi = bias[n];
#pragma unroll
    for (int mi = 0; mi < 4; ++mi) {
      const int m = wm * 64 + mi * 16 + fq * 4;
#pragma unroll
      for (int r = 0; r < 4; ++r) {
        const float v = fmaxf(acc[mi][nj][r] + bi, 0.f);
        if (Oh) {
          const u16 h = f2bf(v);
          Oh[(size_t)(m + r) * 1024 + n] = h;
          Ol[(size_t)(m + r) * 1024 + n] = f2bf(v - bf2f(h));
        } else {
          Of[(size_t)(m + r) * 1024 + n] = v;
        }
      }
    }
  }
}

__global__ __launch_bounds__(256)
void out_kernel(const float* __restrict__ T2, const float* __restrict__ Wout,
                const float* __restrict__ bout, float* __restrict__ out) {
  const int b = blockIdx.x;
  const int t = threadIdx.x;  // 256
  float a0 = 0.f, a1 = 0.f, a2 = 0.f;
  for (int k = t; k < 1024; k += 256) {
    const float x = T2[(size_t)b * 1024 + k];
    a0 = fmaf(x, Wout[k * 3 + 0], a0);
    a1 = fmaf(x, Wout[k * 3 + 1], a1);
    a2 = fmaf(x, Wout[k * 3 + 2], a2);
  }
  __shared__ float red[3][256];
  red[0][t] = a0; red[1][t] = a1; red[2][t] = a2;
  __syncthreads();
  for (int off = 128; off > 0; off >>= 1) {
    if (t < off) {
      red[0][t] += red[0][t + off];
      red[1][t] += red[1][t + off];
      red[2][t] += red[2][t + off];
    }
    __syncthreads();
  }
  if (t < 3) out[b * 3 + t] = red[t][0] + bout[t];
}

extern "C" void kernel_launch(void* const* d_in, const int* in_sizes, int n_in,
                              void* d_out, int out_size, void* d_ws, size_t ws_size,
                              hipStream_t stream) {
  (void)in_sizes; (void)n_in; (void)out_size; (void)ws_size;
  const float* embed = (const float*)d_in[0];
  const float* W1f   = (const float*)d_in[1];
  const float* W1r   = (const float*)d_in[2];
  const float* b1    = (const float*)d_in[3];
  const float* bn1g  = (const float*)d_in[4];
  const float* bn1b  = (const float*)d_in[5];
  const float* W2    = (const float*)d_in[6];
  const float* b2    = (const float*)d_in[7];
  const float* bn2g  = (const float*)d_in[8];
  const float* bn2b  = (const float*)d_in[9];
  const float* Wg    = (const float*)d_in[10];
  const float* bg    = (const float*)d_in[11];
  const float* Wf1   = (const float*)d_in[12];
  const float* bf1   = (const float*)d_in[13];
  const float* Wf2   = (const float*)d_in[14];
  const float* bf2   = (const float*)d_in[15];
  const float* Wout  = (const float*)d_in[16];
  const float* bout  = (const float*)d_in[17];
  const int* ids1    = (const int*)d_in[18];
  const int* ids2    = (const int*)d_in[19];

  char* wsp = (char*)d_ws;
  auto alloc = [&](size_t bytes) {
    char* p = wsp;
    wsp += (bytes + 255) & ~(size_t)255;
    return p;
  };
  u16* Hbf1  = (u16*)alloc((size_t)MROWS * DD * 2);
  u16* Hbf2  = (u16*)alloc((size_t)MROWS * DD * 2);
  u16* HT1   = (u16*)alloc((size_t)MROWS * DD * 2);
  u16* HT2   = (u16*)alloc((size_t)MROWS * DD * 2);
  u16* Xbf1  = (u16*)alloc((size_t)MROWS * 320 * 2);
  u16* Xbf2  = (u16*)alloc((size_t)MROWS * 320 * 2);
  u16* BETAb = (u16*)alloc((size_t)MROWS * DD * 2);
  u16* ALPHAb= (u16*)alloc((size_t)MROWS * DD * 2);
  float* SQP1= (float*)alloc((size_t)8 * MROWS * 4);
  float* SQP2= (float*)alloc((size_t)8 * MROWS * 4);
  u16* Wt1f  = (u16*)alloc((size_t)DD * 320 * 2);
  u16* Wt1r  = (u16*)alloc((size_t)9 * DD * DD * 2);
  u16* Wt2   = (u16*)alloc((size_t)10 * DD * 2 * DD * 2);
  u16* Wtg   = (u16*)alloc((size_t)10 * DD * DD * 2);
  u16* Wf1t  = (u16*)alloc((size_t)1024 * 1024 * 2);
  u16* Wf2t  = (u16*)alloc((size_t)1024 * 1024 * 2);
  u16* VPh   = (u16*)alloc((size_t)128 * 1024 * 2);
  u16* VPl   = (u16*)alloc((size_t)128 * 1024 * 2);
  u16* T1h   = (u16*)alloc((size_t)128 * 1024 * 2);
  u16* T1l   = (u16*)alloc((size_t)128 * 1024 * 2);
  float* T2f = (float*)alloc((size_t)128 * 1024 * 4);

  k_prep<<<512, 256, 0, stream>>>(W1f, W1r, W2, Wg, Wf1, Wf2,
                                  Wt1f, Wt1r, Wt2, Wtg, Wf1t, Wf2t,
                                  embed, ids1, ids2, Xbf1, Xbf2, VPh, VPl);

  for (int i = 0; i < NLAYERS; ++i) {
    const u16* Wt1 = (i == 0) ? Wt1f : (Wt1r + (size_t)(i - 1) * DD * DD);
    const int K1 = (i == 0) ? 320 : DD;
    mfma_lbr<<<dim3(MROWS / 128, 4, 2), 256, 0, stream>>>(
        Xbf1, Xbf2, K1, K1, Wt1, b1 + i * DD, bn1g + i * DD, bn1b + i * DD,
        Hbf1, Hbf2, HT1, HT2, SQP1, SQP2);
    attf<<<dim3(NB, 2, 2), 256, 0, stream>>>(Hbf1, Hbf2, SQP1, SQP2, HT1, HT2,
                                             BETAb, ALPHAb);
    mfma_vg<<<dim3(MROWS / 128, 4, 2), 256, 0, stream>>>(
        Hbf1, Hbf2, BETAb, ALPHAb, Wt2 + (size_t)i * DD * 2 * DD,
        Wtg + (size_t)i * DD * DD, b2 + i * DD, bn2g + i * DD, bn2b + i * DD,
        bg + i * DD, Xbf1, Xbf2, (i == NLAYERS - 1) ? 1 : 0, VPh, VPl);
  }
  mlp_full<<<8, 256, 0, stream>>>(VPh, VPl, Wf1t, bf1, T1h, T1l, nullptr);
  mlp_full<<<8, 256, 0, stream>>>(T1h, T1l, Wf2t, bf2, nullptr, nullptr, T2f);
  out_kernel<<<NB, 256, 0, stream>>>(T2f, Wout, bout, (float*)d_out);
}

// Round 15
// 485.942 us; speedup vs baseline: 1.2267x; 1.2267x over previous
//
#include <hip/hip_runtime.h>
#include <hip/hip_bf16.h>
#include <cstddef>

// Problem constants
#define NB 64      // batch
#define LL 128     // L1 == L2
#define EE 300     // embed dim
#define DD 256     // hidden dim
#define NLAYERS 10
#define MROWS (NB * LL)  // 8192

static constexpr float BN_SC = 0.9995003746877562f;  // 1/sqrt(1+1e-3)

typedef unsigned short u16;
typedef __attribute__((ext_vector_type(4))) unsigned short us4;
typedef __attribute__((ext_vector_type(8))) unsigned short us8;
typedef __attribute__((ext_vector_type(8))) short bfrag;   // 8 bf16 (4 VGPR)
typedef __attribute__((ext_vector_type(4))) float f4;      // MFMA C/D

#define MFMA_B16(a, b, c) __builtin_amdgcn_mfma_f32_16x16x32_bf16(a, b, c, 0, 0, 0)

__device__ __forceinline__ u16 f2bf(float x) {
  union { float f; unsigned u; } v; v.f = x;
  unsigned r = v.u + 0x7FFFu + ((v.u >> 16) & 1u);  // RNE
  return (u16)(r >> 16);
}
__device__ __forceinline__ float bf2f(u16 s) {
  union { unsigned u; float f; } v; v.u = (unsigned)s << 16;
  return v.f;
}
__device__ __forceinline__ float4 ld4(const float* p) { return *(const float4*)p; }

// ---------------- async global->LDS staging (16B/lane) -------------------
__device__ __forceinline__ void async16(void* lds, const void* g) {
  __builtin_amdgcn_global_load_lds(
      (const __attribute__((address_space(1))) unsigned int*)g,
      (__attribute__((address_space(3))) unsigned int*)lds, 16, 0, 0);
}

// ===== BK=64 tiles, XOR-swizzled (byte ^= (row&7)<<4) ====================
__device__ __forceinline__ int swz64(int row, int colbyte) {
  return (row * 128 + colbyte) ^ ((row & 7) << 4);
}
__device__ __forceinline__ bfrag ldsT(const u16* T, int row, int colbyte) {
  return *(const bfrag*)((const char*)T + swz64(row, colbyte));
}

// [128 rows][64 k] (16KB): 4 async16/thread, source part pre-swizzled.
__device__ __forceinline__ void stage128x64(const u16* __restrict__ src, int ld,
                                            int r0, int k0, u16* lds, int t) {
  const int w = t >> 6;
#pragma unroll
  for (int j = 0; j < 4; ++j) {
    const int c = j * 256 + t;         // chunk 0..1023
    const int row = c >> 3, part = c & 7;
    const int sp = part ^ (row & 7);
    async16((char*)lds + j * 4096 + w * 1024,
            src + (size_t)(r0 + row) * ld + k0 + sp * 8);
  }
}
// [64 rows][64 k] (8KB): 2 async16/thread.
__device__ __forceinline__ void stage64x64(const u16* __restrict__ src, int ld,
                                           int r0, int k0, u16* lds, int t) {
  const int w = t >> 6;
#pragma unroll
  for (int j = 0; j < 2; ++j) {
    const int c = j * 256 + t;         // chunk 0..511
    const int row = c >> 3, part = c & 7;
    const int sp = part ^ (row & 7);
    async16((char*)lds + j * 4096 + w * 1024,
            src + (size_t)(r0 + row) * ld + k0 + sp * 8);
  }
}

// 128m x 64n over K=64 (2 MFMA sub-steps): swizzled reads.
__device__ __forceinline__ void step_k64(const u16* As, const u16* Bs, int wm,
                                         int wn, int fr, int fq, f4 acc[4][2]) {
#pragma unroll
  for (int ks2 = 0; ks2 < 2; ++ks2) {
    bfrag a[4], b[2];
#pragma unroll
    for (int i = 0; i < 4; ++i)
      a[i] = ldsT(As, wm * 64 + i * 16 + fr, ks2 * 64 + fq * 16);
#pragma unroll
    for (int j = 0; j < 2; ++j)
      b[j] = ldsT(Bs, wn * 32 + j * 16 + fr, ks2 * 64 + fq * 16);
#pragma unroll
    for (int i = 0; i < 4; ++i)
#pragma unroll
      for (int j = 0; j < 2; ++j) acc[i][j] = MFMA_B16(a[i], b[j], acc[i][j]);
  }
}

__device__ __forceinline__ void step2_k64(const u16* As, const u16* B2s,
                                          const u16* Bgs, int wm, int wn,
                                          int fr, int fq, f4 accv[4][2],
                                          f4 accg[4][2]) {
#pragma unroll
  for (int ks2 = 0; ks2 < 2; ++ks2) {
    bfrag a[4], b2[2], bg[2];
#pragma unroll
    for (int i = 0; i < 4; ++i)
      a[i] = ldsT(As, wm * 64 + i * 16 + fr, ks2 * 64 + fq * 16);
#pragma unroll
    for (int j = 0; j < 2; ++j) {
      b2[j] = ldsT(B2s, wn * 32 + j * 16 + fr, ks2 * 64 + fq * 16);
      bg[j] = ldsT(Bgs, wn * 32 + j * 16 + fr, ks2 * 64 + fq * 16);
    }
#pragma unroll
    for (int i = 0; i < 4; ++i)
#pragma unroll
      for (int j = 0; j < 2; ++j) {
        accv[i][j] = MFMA_B16(a[i], b2[j], accv[i][j]);
        accg[i][j] = MFMA_B16(a[i], bg[j], accg[i][j]);
      }
  }
}

// direct MFMA fragment load from row-major [row][k] bf16 global (L2-hot)
__device__ __forceinline__ bfrag gfrag(const u16* __restrict__ p, int ld, int row, int k) {
  return *(const bfrag*)(p + (size_t)row * ld + k);
}

// swizzled byte offset into a [128][128] bf16 LDS matrix (conflict-free b128 reads)
__device__ __forceinline__ int eswz(int row, int colbyte) {
  return (row * 256 + colbyte) ^ ((row & 7) << 4);
}
__device__ __forceinline__ bfrag ldsE(const u16* E, int row, int colbyte) {
  return *(const bfrag*)((const char*)E + eswz(row, colbyte));
}

// ---------------- fused prologue: weight transposes + gather + VP pad ----
__device__ void txw_tile(const float* __restrict__ src, u16* __restrict__ dst,
                         int K, int N, int Kpad, int k0, int n0, int t,
                         float (*tileS)[65]) {
  __syncthreads();  // protect LDS across task iterations
  {
    const int kr = t >> 2, nc = (t & 3) * 16;
    const int k = k0 + kr;
#pragma unroll
    for (int j = 0; j < 16; j += 4) {
      float4 v = (k < K) ? ld4(src + (size_t)k * N + n0 + nc + j)
                         : make_float4(0.f, 0.f, 0.f, 0.f);
      tileS[kr][nc + j + 0] = v.x; tileS[kr][nc + j + 1] = v.y;
      tileS[kr][nc + j + 2] = v.z; tileS[kr][nc + j + 3] = v.w;
    }
  }
  __syncthreads();
  {
    const int nr = t >> 2, kc = (t & 3) * 16;
    us8 o0, o1;
#pragma unroll
    for (int j = 0; j < 8; ++j) {
      o0[j] = f2bf(tileS[kc + j][nr]);
      o1[j] = f2bf(tileS[kc + 8 + j][nr]);
    }
    u16* d = dst + (size_t)(n0 + nr) * Kpad + k0 + kc;
    *(us8*)d = o0;
    *(us8*)(d + 8) = o1;
  }
}

__global__ __launch_bounds__(256)
void k_prep(const float* __restrict__ W1f, const float* __restrict__ W1r,
            const float* __restrict__ W2, const float* __restrict__ Wg,
            const float* __restrict__ Wf1, const float* __restrict__ Wf2,
            u16* __restrict__ Wt1f, u16* __restrict__ Wt1r,
            u16* __restrict__ Wt2, u16* __restrict__ Wtg,
            u16* __restrict__ Wf1t, u16* __restrict__ Wf2t,
            const float* __restrict__ embed, const int* __restrict__ ids1,
            const int* __restrict__ ids2, u16* __restrict__ X1,
            u16* __restrict__ X2, u16* __restrict__ VPh, u16* __restrict__ VPl) {
  __shared__ float tileS[64][65];
  const int t = threadIdx.x;
  const int blk = blockIdx.x, nblk = gridDim.x;
  for (int it = blk; it < 20; it += nblk)
    txw_tile(W1f, Wt1f, 300, 256, 320, (it % 5) * 64, (it / 5) * 64, t, tileS);
  for (int it = blk; it < 144; it += nblk) {
    const int l = it / 16, r = it % 16;
    txw_tile(W1r + (size_t)l * 65536, Wt1r + (size_t)l * 65536, 256, 256, 256,
             (r % 4) * 64, (r / 4) * 64, t, tileS);
  }
  for (int it = blk; it < 320; it += nblk) {
    const int l = it / 32, r = it % 32;
    txw_tile(W2 + (size_t)l * 131072, Wt2 + (size_t)l * 131072, 512, 256, 512,
             (r % 8) * 64, (r / 8) * 64, t, tileS);
  }
  for (int it = blk; it < 160; it += nblk) {
    const int l = it / 16, r = it % 16;
    txw_tile(Wg + (size_t)l * 65536, Wtg + (size_t)l * 65536, 256, 256, 256,
             (r % 4) * 64, (r / 4) * 64, t, tileS);
  }
  for (int it = blk; it < 256; it += nblk)
    txw_tile(Wf1, Wf1t, 1024, 1024, 1024, (it % 16) * 64, (it / 16) * 64, t, tileS);
  for (int it = blk; it < 256; it += nblk)
    txw_tile(Wf2, Wf2t, 1024, 1024, 1024, (it % 16) * 64, (it / 16) * 64, t, tileS);
  for (int g = blk; g < 4096; g += nblk) {
    const int side = g & 1;
    const int* ids = side ? ids2 : ids1;
    u16* E = side ? X2 : X1;
    const int row = (g >> 1) * 4 + (t >> 6);
    const int lane = t & 63;
    const float* src = embed + (size_t)ids[row] * EE;
    u16* dst = E + (size_t)row * 320;
#pragma unroll
    for (int j = 0; j < 5; ++j) {
      const int c = lane + 64 * j;
      dst[c] = f2bf(c < EE ? src[c] : 0.f);
    }
  }
  // zero the MLP pad rows 64..127 of VPh/VPl
  for (int it = blk; it < 128; it += nblk) {
    const int arr = it & 1, row = 64 + (it >> 1);
    u16* dst = (arr ? VPl : VPh) + (size_t)row * 1024;
#pragma unroll
    for (int j = 0; j < 4; ++j) dst[t * 4 + j] = 0;
  }
}

// --- LBR-1 n64 BK=64 swizzled, depth-2 counted-vmcnt pipeline (T4) -------
__global__ __launch_bounds__(256, 2)
void mfma_lbr(const u16* __restrict__ A0, const u16* __restrict__ A1, int lda,
              int K, const u16* __restrict__ Wt, const float* __restrict__ bias,
              const float* __restrict__ gam, const float* __restrict__ bet,
              u16* __restrict__ O0, u16* __restrict__ O1,
              u16* __restrict__ HTa, u16* __restrict__ HTb,
              float* __restrict__ SQPa, float* __restrict__ SQPb) {
  const int side = blockIdx.z;
  const u16* A = side ? A1 : A0;
  u16* O = side ? O1 : O0;
  u16* HT = side ? HTb : HTa;
  float* SQP = side ? SQPb : SQPa;
  __shared__ u16 As[3][128 * 64], Bs[3][64 * 64];  // 48KB + 24KB
  const int t = threadIdx.x;
  const int m0 = blockIdx.x * 128, n0 = blockIdx.y * 64;
  const int lane = t & 63, w = t >> 6, wm = w >> 1, wn = w & 1;
  const int fr = lane & 15, fq = lane >> 4;
  f4 acc[4][2] = {};
  const int nt = K / 64;  // 4 (K=256) or 5 (K=320)
  stage128x64(A, lda, m0, 0, As[0], t);
  stage64x64(Wt, K, n0, 0, Bs[0], t);
  stage128x64(A, lda, m0, 64, As[1], t);
  stage64x64(Wt, K, n0, 64, Bs[1], t);
  for (int ks = 0; ks < nt; ++ks) {
    if (ks < nt - 1) asm volatile("s_waitcnt vmcnt(6)" ::: "memory");
    else             asm volatile("s_waitcnt vmcnt(0)" ::: "memory");
    __builtin_amdgcn_sched_barrier(0);
    __builtin_amdgcn_s_barrier();
    if (ks + 2 < nt) {
      stage128x64(A, lda, m0, (ks + 2) * 64, As[(ks + 2) % 3], t);
      stage64x64(Wt, K, n0, (ks + 2) * 64, Bs[(ks + 2) % 3], t);
    }
    step_k64(As[ks % 3], Bs[ks % 3], wm, wn, fr, fq, acc);
  }
  const int b = m0 >> 7;
  float rsq[4][4] = {};
#pragma unroll
  for (int nj = 0; nj < 2; ++nj) {
    const int n = n0 + wn * 32 + nj * 16 + fr;
    const float sc = gam[n] * BN_SC, bi = bias[n], be = bet[n];
#pragma unroll
    for (int mi = 0; mi < 4; ++mi) {
      const int m = m0 + wm * 64 + mi * 16 + fq * 4;
      us4 pk;
#pragma unroll
      for (int r = 0; r < 4; ++r) {
        const float x = sc * (acc[mi][nj][r] + bi) + be;
        const u16 hb = f2bf(fmaxf(x, 0.f));
        O[(size_t)(m + r) * DD + n] = hb;
        pk[r] = hb;
        const float h = bf2f(hb);  // norms must match stored bf16 H
        rsq[mi][r] += h * h;
      }
      *(us4*)&HT[((size_t)b * DD + n) * LL + (m & 127)] = pk;
    }
  }
#pragma unroll
  for (int mi = 0; mi < 4; ++mi)
#pragma unroll
    for (int r = 0; r < 4; ++r) {
      float v = rsq[mi][r];
      v += __shfl_xor(v, 1, 64); v += __shfl_xor(v, 2, 64);
      v += __shfl_xor(v, 4, 64); v += __shfl_xor(v, 8, 64);
      rsq[mi][r] = v;
    }
  if (fr == 0) {
    const int p = blockIdx.y * 2 + wn;  // 8 partials per row
#pragma unroll
    for (int mi = 0; mi < 4; ++mi)
#pragma unroll
      for (int r = 0; r < 4; ++r)
        SQP[(size_t)p * MROWS + m0 + wm * 64 + mi * 16 + fq * 4 + r] = rsq[mi][r];
  }
}

// ------- fused att+attn per (batch, N-half, side): E in LDS, PV out ------
__global__ __launch_bounds__(256, 2)
void attf(const u16* __restrict__ H1, const u16* __restrict__ H2,
          const float* __restrict__ SQP1, const float* __restrict__ SQP2,
          const u16* __restrict__ HT1, const u16* __restrict__ HT2,
          u16* __restrict__ BETA, u16* __restrict__ ALPHA) {
  const int b = blockIdx.x, nh = blockIdx.y, side = blockIdx.z;
  __shared__ u16 Elds[128 * 128];  // 32KB swizzled (Ê or Ê^T per side)
  __shared__ float sqs[2][128], rowp[2][128], colp[2][128];
  const int t = threadIdx.x, lane = t & 63, w = t >> 6;
  const int wm = w >> 1, wn = w & 1;
  const int fr = lane & 15, fq = lane >> 4;
  const int r0 = b * LL;
  if (t < 128) {
    float s = 0.f;
#pragma unroll
    for (int p = 0; p < 8; ++p) s += SQP1[(size_t)p * MROWS + r0 + t];
    sqs[0][t] = s;
  } else {
    const int u = t - 128;
    float s = 0.f;
#pragma unroll
    for (int p = 0; p < 8; ++p) s += SQP2[(size_t)p * MROWS + r0 + u];
    sqs[1][u] = s;
  }
  // QK^T: full 128x128 E, no-LDS frag loads
  f4 acc[4][4] = {};
#pragma unroll
  for (int ks = 0; ks < 8; ++ks) {
    bfrag a[4], bv[4];
#pragma unroll
    for (int mi = 0; mi < 4; ++mi)
      a[mi] = gfrag(H1, DD, r0 + wm * 64 + mi * 16 + fr, ks * 32 + fq * 8);
#pragma unroll
    for (int nj = 0; nj < 4; ++nj)
      bv[nj] = gfrag(H2, DD, r0 + wn * 64 + nj * 16 + fr, ks * 32 + fq * 8);
#pragma unroll
    for (int mi = 0; mi < 4; ++mi)
#pragma unroll
      for (int nj = 0; nj < 4; ++nj) acc[mi][nj] = MFMA_B16(a[mi], bv[nj], acc[mi][nj]);
  }
  __syncthreads();  // sqs visible
  float rp[4][4] = {}, cp[4] = {};
#pragma unroll
  for (int nj = 0; nj < 4; ++nj) {
    const int n = wn * 64 + nj * 16 + fr;
    const float s2 = sqs[1][n];
#pragma unroll
    for (int mi = 0; mi < 4; ++mi) {
      const int m = wm * 64 + mi * 16 + fq * 4;
#pragma unroll
      for (int r = 0; r < 4; ++r) {
        const float d = sqs[0][m + r] + s2 - 2.f * acc[mi][nj][r];
        const float e = __expf(1.f / (1.f + d));
        acc[mi][nj][r] = e;
        rp[mi][r] += e;
        cp[nj] += e;
      }
    }
  }
#pragma unroll
  for (int mi = 0; mi < 4; ++mi)
#pragma unroll
    for (int r = 0; r < 4; ++r) {
      float v = rp[mi][r];
      v += __shfl_xor(v, 1, 64); v += __shfl_xor(v, 2, 64);
      v += __shfl_xor(v, 4, 64); v += __shfl_xor(v, 8, 64);
      rp[mi][r] = v;
    }
#pragma unroll
  for (int nj = 0; nj < 4; ++nj) {
    float v = cp[nj];
    v += __shfl_xor(v, 16, 64); v += __shfl_xor(v, 32, 64);
    cp[nj] = v;
  }
  if (fr == 0)
#pragma unroll
    for (int mi = 0; mi < 4; ++mi)
#pragma unroll
      for (int r = 0; r < 4; ++r)
        rowp[wn][wm * 64 + mi * 16 + fq * 4 + r] = rp[mi][r];
  if (fq == 0)
#pragma unroll
    for (int nj = 0; nj < 4; ++nj)
      colp[wm][wn * 64 + nj * 16 + fr] = cp[nj];
  __syncthreads();
  if (side == 0) {  // row-normalized Ê
#pragma unroll
    for (int nj = 0; nj < 4; ++nj) {
      const int n = wn * 64 + nj * 16 + fr;
#pragma unroll
      for (int mi = 0; mi < 4; ++mi) {
        const int m = wm * 64 + mi * 16 + fq * 4;
#pragma unroll
        for (int r = 0; r < 4; ++r) {
          const float riv = 1.f / (rowp[0][m + r] + rowp[1][m + r]);
          *(u16*)((char*)Elds + eswz(m + r, n * 2)) = f2bf(acc[mi][nj][r] * riv);
        }
      }
    }
  } else {  // col-normalized Ê^T
#pragma unroll
    for (int nj = 0; nj < 4; ++nj) {
      const int n = wn * 64 + nj * 16 + fr;
      const float civ = 1.f / (colp[0][n] + colp[1][n]);
#pragma unroll
      for (int mi = 0; mi < 4; ++mi) {
        const int m = wm * 64 + mi * 16 + fq * 4;
        us4 pk;
#pragma unroll
        for (int r = 0; r < 4; ++r) pk[r] = f2bf(acc[mi][nj][r] * civ);
        *(us4*)((char*)Elds + eswz(n, m * 2)) = pk;
      }
    }
  }
  __syncthreads();
  // PV: O = Ê @ H (B-frags from HT rows = H columns), this block's 128-col half
  const u16* HT = side ? HT1 : HT2;
  f4 pv[4][4] = {};
#pragma unroll
  for (int ks = 0; ks < 4; ++ks) {
    bfrag a[4], bv[4];
#pragma unroll
    for (int mi = 0; mi < 4; ++mi)
      a[mi] = ldsE(Elds, wm * 64 + mi * 16 + fr, ks * 64 + fq * 16);
#pragma unroll
    for (int nj = 0; nj < 4; ++nj)
      bv[nj] = gfrag(HT, LL, b * DD + nh * 128 + wn * 64 + nj * 16 + fr, ks * 32 + fq * 8);
#pragma unroll
    for (int mi = 0; mi < 4; ++mi)
#pragma unroll
      for (int nj = 0; nj < 4; ++nj) pv[mi][nj] = MFMA_B16(a[mi], bv[nj], pv[mi][nj]);
  }
  u16* O = side ? ALPHA : BETA;
#pragma unroll
  for (int nj = 0; nj < 4; ++nj) {
    const int n = nh * 128 + wn * 64 + nj * 16 + fr;
#pragma unroll
    for (int mi = 0; mi < 4; ++mi) {
      const int m = wm * 64 + mi * 16 + fq * 4;
#pragma unroll
      for (int r = 0; r < 4; ++r)
        O[(size_t)(r0 + m + r) * DD + n] = f2bf(pv[mi][nj][r]);
    }
  }
}

// --- vg n64 BK=64 swizzled: W2 || Wg + gate update (+pool on last) -------
__global__ __launch_bounds__(256, 2)
void mfma_vg(const u16* __restrict__ Hbf1, const u16* __restrict__ Hbf2,
             const u16* __restrict__ BETA, const u16* __restrict__ ALPHA,
             const u16* __restrict__ Wt2, const u16* __restrict__ Wtg,
             const float* __restrict__ b2, const float* __restrict__ g2,
             const float* __restrict__ be2, const float* __restrict__ bgv,
             u16* __restrict__ X0, u16* __restrict__ X1p, int dopool,
             u16* __restrict__ VPh, u16* __restrict__ VPl) {
  const int side = blockIdx.z;
  const u16* H = side ? Hbf2 : Hbf1;
  const u16* CC = side ? ALPHA : BETA;
  u16* X = side ? X1p : X0;
  const int m0 = blockIdx.x * 128, n0 = blockIdx.y * 64;
  __shared__ u16 As[2][128 * 64], B2s[2][64 * 64], Bgs[2][64 * 64];  // 64KB
  __shared__ float pmx[2][64], psm[2][64];
  const int t = threadIdx.x;
  const int lane = t & 63, w = t >> 6, wm = w >> 1, wn = w & 1;
  const int fr = lane & 15, fq = lane >> 4;
  f4 accv[4][2] = {}, accg[4][2] = {};
  stage128x64(H, DD, m0, 0, As[0], t);
  stage64x64(Wt2, 2 * DD, n0, 0, B2s[0], t);
  stage64x64(Wtg, DD, n0, 0, Bgs[0], t);
  __syncthreads();
  for (int ks = 0; ks < 8; ++ks) {
    const int cur = ks & 1;
    if (ks + 1 < 8) {
      const u16* Asrc = (ks + 1 < 4) ? H : CC;
      stage128x64(Asrc, DD, m0, ((ks + 1) & 3) * 64, As[cur ^ 1], t);
      stage64x64(Wt2, 2 * DD, n0, (ks + 1) * 64, B2s[cur ^ 1], t);
      if (ks + 1 < 4) stage64x64(Wtg, DD, n0, (ks + 1) * 64, Bgs[cur ^ 1], t);
    }
    if (ks < 4)
      step2_k64(As[cur], B2s[cur], Bgs[cur], wm, wn, fr, fq, accv, accg);
    else
      step_k64(As[cur], B2s[cur], wm, wn, fr, fq, accv);
    __syncthreads();
  }
  float pmax[2] = {-1e30f, -1e30f}, psum[2] = {0.f, 0.f};
#pragma unroll
  for (int nj = 0; nj < 2; ++nj) {
    const int n = n0 + wn * 32 + nj * 16 + fr;
    const float sc = g2[n] * BN_SC, bi = b2[n], be = be2[n], bgn = bgv[n];
#pragma unroll
    for (int mi = 0; mi < 4; ++mi) {
      const int m = m0 + wm * 64 + mi * 16 + fq * 4;
#pragma unroll
      for (int r = 0; r < 4; ++r) {
        const float v = fmaxf(sc * (accv[mi][nj][r] + bi) + be, 0.f);
        const float g = 1.f / (1.f + __expf(-(accg[mi][nj][r] + bgn)));
        const float h = bf2f(H[(size_t)(m + r) * DD + n]);
        const u16 xb = f2bf(v * g + h * (1.f - g));
        X[(size_t)(m + r) * DD + n] = xb;
        if (dopool) {
          const float xv = bf2f(xb);
          pmax[nj] = fmaxf(pmax[nj], xv);
          psum[nj] += xv;
        }
      }
    }
  }
  if (dopool) {
#pragma unroll
    for (int nj = 0; nj < 2; ++nj) {
      float mx = pmax[nj], sm = psum[nj];
      mx = fmaxf(mx, __shfl_xor(mx, 16, 64)); sm += __shfl_xor(sm, 16, 64);
      mx = fmaxf(mx, __shfl_xor(mx, 32, 64)); sm += __shfl_xor(sm, 32, 64);
      if (fq == 0) {
        pmx[wm][wn * 32 + nj * 16 + fr] = mx;
        psm[wm][wn * 32 + nj * 16 + fr] = sm;
      }
    }
    __syncthreads();
    if (t < 64) {
      const float mx = fmaxf(pmx[0][t], pmx[1][t]);
      const float sm = psm[0][t] + psm[1][t];
      const int b = m0 >> 7;
      const int col = n0 + t;
      const u16 mh = f2bf(mx);
      VPh[(size_t)b * 1024 + side * 256 + col] = mh;
      VPl[(size_t)b * 1024 + side * 256 + col] = f2bf(mx - bf2f(mh));
      const u16 sh = f2bf(sm);
      VPh[(size_t)b * 1024 + (2 + side) * 256 + col] = sh;
      VPl[(size_t)b * 1024 + (2 + side) * 256 + col] = f2bf(sm - bf2f(sh));
    }
  }
}

// ---------------- MLP split-K no-LDS: PART[slice] = (Ah+Al) @ Wt-slice ---
__global__ __launch_bounds__(256, 2)
void mlp_sk(const u16* __restrict__ Ah, const u16* __restrict__ Al,
            const u16* __restrict__ Wt, float* __restrict__ PART) {
  const int n0 = blockIdx.x * 128;   // 8 N-blocks
  const int k0 = blockIdx.y * 128;   // 8 K-slices
  const int t = threadIdx.x, lane = t & 63, w = t >> 6;
  const int wm = w >> 1, wn = w & 1;
  const int fr = lane & 15, fq = lane >> 4;
  f4 acc[4][4] = {};
#pragma unroll
  for (int ks = 0; ks < 4; ++ks) {
    bfrag ah[4], al[4], bv[4];
#pragma unroll
    for (int mi = 0; mi < 4; ++mi) {
      ah[mi] = gfrag(Ah, 1024, wm * 64 + mi * 16 + fr, k0 + ks * 32 + fq * 8);
      al[mi] = gfrag(Al, 1024, wm * 64 + mi * 16 + fr, k0 + ks * 32 + fq * 8);
    }
#pragma unroll
    for (int nj = 0; nj < 4; ++nj)
      bv[nj] = gfrag(Wt, 1024, n0 + wn * 64 + nj * 16 + fr, k0 + ks * 32 + fq * 8);
#pragma unroll
    for (int mi = 0; mi < 4; ++mi)
#pragma unroll
      for (int nj = 0; nj < 4; ++nj) {
        acc[mi][nj] = MFMA_B16(ah[mi], bv[nj], acc[mi][nj]);
        acc[mi][nj] = MFMA_B16(al[mi], bv[nj], acc[mi][nj]);
      }
  }
#pragma unroll
  for (int nj = 0; nj < 4; ++nj) {
    const int n = n0 + wn * 64 + nj * 16 + fr;
#pragma unroll
    for (int mi = 0; mi < 4; ++mi) {
      const int m = wm * 64 + mi * 16 + fq * 4;
#pragma unroll
      for (int r = 0; r < 4; ++r)
        PART[((size_t)blockIdx.y * 128 + m + r) * 1024 + n] = acc[mi][nj][r];
    }
  }
}

// combine 8 partials + bias + relu -> hi/lo bf16 (first MLP)
__global__ __launch_bounds__(512)
void mlp_comb(const float* __restrict__ P, const float* __restrict__ bias,
              u16* __restrict__ Oh, u16* __restrict__ Ol) {
#pragma unroll
  for (int e = 0; e < 8; ++e) {
    const int idx = blockIdx.x * 4096 + e * 512 + threadIdx.x;
    const int col = idx & 1023;
    float s = bias[col];
#pragma unroll
    for (int p = 0; p < 8; ++p) s += P[(size_t)p * 131072 + idx];
    s = fmaxf(s, 0.f);
    const u16 h = f2bf(s);
    Oh[idx] = h;
    Ol[idx] = f2bf(s - bf2f(h));
  }
}

// combine 8 partials + bias + relu + final Wout dot -> logits (second MLP)
__global__ __launch_bounds__(512)
void mlp_comb_out(const float* __restrict__ P, const float* __restrict__ bias,
                  const float* __restrict__ Wout, const float* __restrict__ bout,
                  float* __restrict__ out) {
  __shared__ float red[4][8][3];
  const int t = threadIdx.x;
  float a[4][3] = {};
#pragma unroll
  for (int e = 0; e < 8; ++e) {
    const int idx = blockIdx.x * 4096 + e * 512 + t;
    const int col = idx & 1023;
    float s = bias[col];
#pragma unroll
    for (int p = 0; p < 8; ++p) s += P[(size_t)p * 131072 + idx];
    s = fmaxf(s, 0.f);
    const int lr = e >> 1;  // local row 0..3 (rows blk*4 .. blk*4+3)
    a[lr][0] = fmaf(s, Wout[col * 3 + 0], a[lr][0]);
    a[lr][1] = fmaf(s, Wout[col * 3 + 1], a[lr][1]);
    a[lr][2] = fmaf(s, Wout[col * 3 + 2], a[lr][2]);
  }
  const int lane = t & 63, w = t >> 6;
#pragma unroll
  for (int lr = 0; lr < 4; ++lr)
#pragma unroll
    for (int c = 0; c < 3; ++c) {
      float v = a[lr][c];
#pragma unroll
      for (int off = 32; off > 0; off >>= 1) v += __shfl_down(v, off, 64);
      if (lane == 0) red[lr][w][c] = v;
    }
  __syncthreads();
  if (t < 12) {
    const int lr = t / 3, c = t % 3;
    float s = bout[c];
#pragma unroll
    for (int w8 = 0; w8 < 8; ++w8) s += red[lr][w8][c];
    out[(blockIdx.x * 4 + lr) * 3 + c] = s;
  }
}

extern "C" void kernel_launch(void* const* d_in, const int* in_sizes, int n_in,
                              void* d_out, int out_size, void* d_ws, size_t ws_size,
                              hipStream_t stream) {
  (void)in_sizes; (void)n_in; (void)out_size; (void)ws_size;
  const float* embed = (const float*)d_in[0];
  const float* W1f   = (const float*)d_in[1];
  const float* W1r   = (const float*)d_in[2];
  const float* b1    = (const float*)d_in[3];
  const float* bn1g  = (const float*)d_in[4];
  const float* bn1b  = (const float*)d_in[5];
  const float* W2    = (const float*)d_in[6];
  const float* b2    = (const float*)d_in[7];
  const float* bn2g  = (const float*)d_in[8];
  const float* bn2b  = (const float*)d_in[9];
  const float* Wg    = (const float*)d_in[10];
  const float* bg    = (const float*)d_in[11];
  const float* Wf1   = (const float*)d_in[12];
  const float* bf1   = (const float*)d_in[13];
  const float* Wf2   = (const float*)d_in[14];
  const float* bf2   = (const float*)d_in[15];
  const float* Wout  = (const float*)d_in[16];
  const float* bout  = (const float*)d_in[17];
  const int* ids1    = (const int*)d_in[18];
  const int* ids2    = (const int*)d_in[19];

  char* wsp = (char*)d_ws;
  auto alloc = [&](size_t bytes) {
    char* p = wsp;
    wsp += (bytes + 255) & ~(size_t)255;
    return p;
  };
  u16* Hbf1  = (u16*)alloc((size_t)MROWS * DD * 2);
  u16* Hbf2  = (u16*)alloc((size_t)MROWS * DD * 2);
  u16* HT1   = (u16*)alloc((size_t)MROWS * DD * 2);
  u16* HT2   = (u16*)alloc((size_t)MROWS * DD * 2);
  u16* Xbf1  = (u16*)alloc((size_t)MROWS * 320 * 2);
  u16* Xbf2  = (u16*)alloc((size_t)MROWS * 320 * 2);
  u16* BETAb = (u16*)alloc((size_t)MROWS * DD * 2);
  u16* ALPHAb= (u16*)alloc((size_t)MROWS * DD * 2);
  float* SQP1= (float*)alloc((size_t)8 * MROWS * 4);
  float* SQP2= (float*)alloc((size_t)8 * MROWS * 4);
  u16* Wt1f  = (u16*)alloc((size_t)DD * 320 * 2);
  u16* Wt1r  = (u16*)alloc((size_t)9 * DD * DD * 2);
  u16* Wt2   = (u16*)alloc((size_t)10 * DD * 2 * DD * 2);
  u16* Wtg   = (u16*)alloc((size_t)10 * DD * DD * 2);
  u16* Wf1t  = (u16*)alloc((size_t)1024 * 1024 * 2);
  u16* Wf2t  = (u16*)alloc((size_t)1024 * 1024 * 2);
  u16* VPh   = (u16*)alloc((size_t)128 * 1024 * 2);
  u16* VPl   = (u16*)alloc((size_t)128 * 1024 * 2);
  u16* T1h   = (u16*)alloc((size_t)128 * 1024 * 2);
  u16* T1l   = (u16*)alloc((size_t)128 * 1024 * 2);
  float* PART1 = (float*)alloc((size_t)8 * 128 * 1024 * 4);
  float* PART2 = (float*)alloc((size_t)8 * 128 * 1024 * 4);

  k_prep<<<512, 256, 0, stream>>>(W1f, W1r, W2, Wg, Wf1, Wf2,
                                  Wt1f, Wt1r, Wt2, Wtg, Wf1t, Wf2t,
                                  embed, ids1, ids2, Xbf1, Xbf2, VPh, VPl);

  for (int i = 0; i < NLAYERS; ++i) {
    const u16* Wt1 = (i == 0) ? Wt1f : (Wt1r + (size_t)(i - 1) * DD * DD);
    const int K1 = (i == 0) ? 320 : DD;
    mfma_lbr<<<dim3(MROWS / 128, 4, 2), 256, 0, stream>>>(
        Xbf1, Xbf2, K1, K1, Wt1, b1 + i * DD, bn1g + i * DD, bn1b + i * DD,
        Hbf1, Hbf2, HT1, HT2, SQP1, SQP2);
    attf<<<dim3(NB, 2, 2), 256, 0, stream>>>(Hbf1, Hbf2, SQP1, SQP2, HT1, HT2,
                                             BETAb, ALPHAb);
    mfma_vg<<<dim3(MROWS / 128, 4, 2), 256, 0, stream>>>(
        Hbf1, Hbf2, BETAb, ALPHAb, Wt2 + (size_t)i * DD * 2 * DD,
        Wtg + (size_t)i * DD * DD, b2 + i * DD, bn2g + i * DD, bn2b + i * DD,
        bg + i * DD, Xbf1, Xbf2, (i == NLAYERS - 1) ? 1 : 0, VPh, VPl);
  }
  mlp_sk<<<dim3(8, 8), 256, 0, stream>>>(VPh, VPl, Wf1t, PART1);
  mlp_comb<<<32, 512, 0, stream>>>(PART1, bf1, T1h, T1l);
  mlp_sk<<<dim3(8, 8), 256, 0, stream>>>(T1h, T1l, Wf2t, PART2);
  mlp_comb_out<<<16, 512, 0, stream>>>(PART2, bf2, Wout, bout, (float*)d_out);
}

// Round 16
// 484.278 us; speedup vs baseline: 1.2309x; 1.0034x over previous
//
#include <hip/hip_runtime.h>
#include <hip/hip_bf16.h>
#include <cstddef>

// Problem constants
#define NB 64      // batch
#define LL 128     // L1 == L2
#define EE 300     // embed dim
#define DD 256     // hidden dim
#define NLAYERS 10
#define MROWS (NB * LL)  // 8192

static constexpr float BN_SC = 0.9995003746877562f;  // 1/sqrt(1+1e-3)

typedef unsigned short u16;
typedef __attribute__((ext_vector_type(4))) unsigned short us4;
typedef __attribute__((ext_vector_type(8))) unsigned short us8;
typedef __attribute__((ext_vector_type(8))) short bfrag;   // 8 bf16 (4 VGPR)
typedef __attribute__((ext_vector_type(4))) float f4;      // MFMA C/D

#define MFMA_B16(a, b, c) __builtin_amdgcn_mfma_f32_16x16x32_bf16(a, b, c, 0, 0, 0)

__device__ __forceinline__ u16 f2bf(float x) {
  union { float f; unsigned u; } v; v.f = x;
  unsigned r = v.u + 0x7FFFu + ((v.u >> 16) & 1u);  // RNE
  return (u16)(r >> 16);
}
__device__ __forceinline__ float bf2f(u16 s) {
  union { unsigned u; float f; } v; v.u = (unsigned)s << 16;
  return v.f;
}
__device__ __forceinline__ float4 ld4(const float* p) { return *(const float4*)p; }

// ---------------- async global->LDS staging (16B/lane) -------------------
__device__ __forceinline__ void async16(void* lds, const void* g) {
  __builtin_amdgcn_global_load_lds(
      (const __attribute__((address_space(1))) unsigned int*)g,
      (__attribute__((address_space(3))) unsigned int*)lds, 16, 0, 0);
}

// ===== BK=64 tiles, XOR-swizzled (byte ^= (row&7)<<4) ====================
__device__ __forceinline__ int swz64(int row, int colbyte) {
  return (row * 128 + colbyte) ^ ((row & 7) << 4);
}
__device__ __forceinline__ bfrag ldsT(const u16* T, int row, int colbyte) {
  return *(const bfrag*)((const char*)T + swz64(row, colbyte));
}

// [128 rows][64 k] (16KB): 4 async16/thread, source part pre-swizzled.
__device__ __forceinline__ void stage128x64(const u16* __restrict__ src, int ld,
                                            int r0, int k0, u16* lds, int t) {
  const int w = t >> 6;
#pragma unroll
  for (int j = 0; j < 4; ++j) {
    const int c = j * 256 + t;         // chunk 0..1023
    const int row = c >> 3, part = c & 7;
    const int sp = part ^ (row & 7);
    async16((char*)lds + j * 4096 + w * 1024,
            src + (size_t)(r0 + row) * ld + k0 + sp * 8);
  }
}
// [64 rows][64 k] (8KB): 2 async16/thread.
__device__ __forceinline__ void stage64x64(const u16* __restrict__ src, int ld,
                                           int r0, int k0, u16* lds, int t) {
  const int w = t >> 6;
#pragma unroll
  for (int j = 0; j < 2; ++j) {
    const int c = j * 256 + t;         // chunk 0..511
    const int row = c >> 3, part = c & 7;
    const int sp = part ^ (row & 7);
    async16((char*)lds + j * 4096 + w * 1024,
            src + (size_t)(r0 + row) * ld + k0 + sp * 8);
  }
}

// 128m x 64n over K=64 (2 MFMA sub-steps): swizzled reads.
__device__ __forceinline__ void step_k64(const u16* As, const u16* Bs, int wm,
                                         int wn, int fr, int fq, f4 acc[4][2]) {
#pragma unroll
  for (int ks2 = 0; ks2 < 2; ++ks2) {
    bfrag a[4], b[2];
#pragma unroll
    for (int i = 0; i < 4; ++i)
      a[i] = ldsT(As, wm * 64 + i * 16 + fr, ks2 * 64 + fq * 16);
#pragma unroll
    for (int j = 0; j < 2; ++j)
      b[j] = ldsT(Bs, wn * 32 + j * 16 + fr, ks2 * 64 + fq * 16);
#pragma unroll
    for (int i = 0; i < 4; ++i)
#pragma unroll
      for (int j = 0; j < 2; ++j) acc[i][j] = MFMA_B16(a[i], b[j], acc[i][j]);
  }
}

__device__ __forceinline__ void step2_k64(const u16* As, const u16* B2s,
                                          const u16* Bgs, int wm, int wn,
                                          int fr, int fq, f4 accv[4][2],
                                          f4 accg[4][2]) {
#pragma unroll
  for (int ks2 = 0; ks2 < 2; ++ks2) {
    bfrag a[4], b2[2], bg[2];
#pragma unroll
    for (int i = 0; i < 4; ++i)
      a[i] = ldsT(As, wm * 64 + i * 16 + fr, ks2 * 64 + fq * 16);
#pragma unroll
    for (int j = 0; j < 2; ++j) {
      b2[j] = ldsT(B2s, wn * 32 + j * 16 + fr, ks2 * 64 + fq * 16);
      bg[j] = ldsT(Bgs, wn * 32 + j * 16 + fr, ks2 * 64 + fq * 16);
    }
#pragma unroll
    for (int i = 0; i < 4; ++i)
#pragma unroll
      for (int j = 0; j < 2; ++j) {
        accv[i][j] = MFMA_B16(a[i], b2[j], accv[i][j]);
        accg[i][j] = MFMA_B16(a[i], bg[j], accg[i][j]);
      }
  }
}

// direct MFMA fragment load from row-major [row][k] bf16 global (L2-hot)
__device__ __forceinline__ bfrag gfrag(const u16* __restrict__ p, int ld, int row, int k) {
  return *(const bfrag*)(p + (size_t)row * ld + k);
}

// swizzled byte offset into a [128][128] bf16 LDS matrix (conflict-free b128 reads)
__device__ __forceinline__ int eswz(int row, int colbyte) {
  return (row * 256 + colbyte) ^ ((row & 7) << 4);
}
__device__ __forceinline__ bfrag ldsE(const u16* E, int row, int colbyte) {
  return *(const bfrag*)((const char*)E + eswz(row, colbyte));
}

// ---------------- fused prologue: weight transposes + gather + VP pad ----
__device__ void txw_tile(const float* __restrict__ src, u16* __restrict__ dst,
                         int K, int N, int Kpad, int k0, int n0, int t,
                         float (*tileS)[65]) {
  __syncthreads();  // protect LDS across task iterations
  {
    const int kr = t >> 2, nc = (t & 3) * 16;
    const int k = k0 + kr;
#pragma unroll
    for (int j = 0; j < 16; j += 4) {
      float4 v = (k < K) ? ld4(src + (size_t)k * N + n0 + nc + j)
                         : make_float4(0.f, 0.f, 0.f, 0.f);
      tileS[kr][nc + j + 0] = v.x; tileS[kr][nc + j + 1] = v.y;
      tileS[kr][nc + j + 2] = v.z; tileS[kr][nc + j + 3] = v.w;
    }
  }
  __syncthreads();
  {
    const int nr = t >> 2, kc = (t & 3) * 16;
    us8 o0, o1;
#pragma unroll
    for (int j = 0; j < 8; ++j) {
      o0[j] = f2bf(tileS[kc + j][nr]);
      o1[j] = f2bf(tileS[kc + 8 + j][nr]);
    }
    u16* d = dst + (size_t)(n0 + nr) * Kpad + k0 + kc;
    *(us8*)d = o0;
    *(us8*)(d + 8) = o1;
  }
}

__global__ __launch_bounds__(256)
void k_prep(const float* __restrict__ W1f, const float* __restrict__ W1r,
            const float* __restrict__ W2, const float* __restrict__ Wg,
            const float* __restrict__ Wf1, const float* __restrict__ Wf2,
            u16* __restrict__ Wt1f, u16* __restrict__ Wt1r,
            u16* __restrict__ Wt2, u16* __restrict__ Wtg,
            u16* __restrict__ Wf1t, u16* __restrict__ Wf2t,
            const float* __restrict__ embed, const int* __restrict__ ids1,
            const int* __restrict__ ids2, u16* __restrict__ X1,
            u16* __restrict__ X2, u16* __restrict__ VPh, u16* __restrict__ VPl) {
  __shared__ float tileS[64][65];
  const int t = threadIdx.x;
  const int blk = blockIdx.x, nblk = gridDim.x;
  for (int it = blk; it < 20; it += nblk)
    txw_tile(W1f, Wt1f, 300, 256, 320, (it % 5) * 64, (it / 5) * 64, t, tileS);
  for (int it = blk; it < 144; it += nblk) {
    const int l = it / 16, r = it % 16;
    txw_tile(W1r + (size_t)l * 65536, Wt1r + (size_t)l * 65536, 256, 256, 256,
             (r % 4) * 64, (r / 4) * 64, t, tileS);
  }
  for (int it = blk; it < 320; it += nblk) {
    const int l = it / 32, r = it % 32;
    txw_tile(W2 + (size_t)l * 131072, Wt2 + (size_t)l * 131072, 512, 256, 512,
             (r % 8) * 64, (r / 8) * 64, t, tileS);
  }
  for (int it = blk; it < 160; it += nblk) {
    const int l = it / 16, r = it % 16;
    txw_tile(Wg + (size_t)l * 65536, Wtg + (size_t)l * 65536, 256, 256, 256,
             (r % 4) * 64, (r / 4) * 64, t, tileS);
  }
  for (int it = blk; it < 256; it += nblk)
    txw_tile(Wf1, Wf1t, 1024, 1024, 1024, (it % 16) * 64, (it / 16) * 64, t, tileS);
  for (int it = blk; it < 256; it += nblk)
    txw_tile(Wf2, Wf2t, 1024, 1024, 1024, (it % 16) * 64, (it / 16) * 64, t, tileS);
  for (int g = blk; g < 4096; g += nblk) {
    const int side = g & 1;
    const int* ids = side ? ids2 : ids1;
    u16* E = side ? X2 : X1;
    const int row = (g >> 1) * 4 + (t >> 6);
    const int lane = t & 63;
    const float* src = embed + (size_t)ids[row] * EE;
    u16* dst = E + (size_t)row * 320;
#pragma unroll
    for (int j = 0; j < 5; ++j) {
      const int c = lane + 64 * j;
      dst[c] = f2bf(c < EE ? src[c] : 0.f);
    }
  }
  // zero the MLP pad rows 64..127 of VPh/VPl
  for (int it = blk; it < 128; it += nblk) {
    const int arr = it & 1, row = 64 + (it >> 1);
    u16* dst = (arr ? VPl : VPh) + (size_t)row * 1024;
#pragma unroll
    for (int j = 0; j < 4; ++j) dst[t * 4 + j] = 0;
  }
}

// --- LBR-1 n64 BK=64 swizzled, depth-2 counted-vmcnt pipeline (T4) -------
__global__ __launch_bounds__(256, 2)
void mfma_lbr(const u16* __restrict__ A0, const u16* __restrict__ A1, int lda,
              int K, const u16* __restrict__ Wt, const float* __restrict__ bias,
              const float* __restrict__ gam, const float* __restrict__ bet,
              u16* __restrict__ O0, u16* __restrict__ O1,
              u16* __restrict__ HTa, u16* __restrict__ HTb,
              float* __restrict__ SQPa, float* __restrict__ SQPb) {
  const int side = blockIdx.z;
  const u16* A = side ? A1 : A0;
  u16* O = side ? O1 : O0;
  u16* HT = side ? HTb : HTa;
  float* SQP = side ? SQPb : SQPa;
  __shared__ u16 As[3][128 * 64], Bs[3][64 * 64];  // 48KB + 24KB
  const int t = threadIdx.x;
  const int m0 = blockIdx.x * 128, n0 = blockIdx.y * 64;
  const int lane = t & 63, w = t >> 6, wm = w >> 1, wn = w & 1;
  const int fr = lane & 15, fq = lane >> 4;
  f4 acc[4][2] = {};
  const int nt = K / 64;  // 4 (K=256) or 5 (K=320)
  stage128x64(A, lda, m0, 0, As[0], t);
  stage64x64(Wt, K, n0, 0, Bs[0], t);
  stage128x64(A, lda, m0, 64, As[1], t);
  stage64x64(Wt, K, n0, 64, Bs[1], t);
  for (int ks = 0; ks < nt; ++ks) {
    if (ks < nt - 1) asm volatile("s_waitcnt vmcnt(6)" ::: "memory");
    else             asm volatile("s_waitcnt vmcnt(0)" ::: "memory");
    __builtin_amdgcn_sched_barrier(0);
    __builtin_amdgcn_s_barrier();
    if (ks + 2 < nt) {
      stage128x64(A, lda, m0, (ks + 2) * 64, As[(ks + 2) % 3], t);
      stage64x64(Wt, K, n0, (ks + 2) * 64, Bs[(ks + 2) % 3], t);
    }
    step_k64(As[ks % 3], Bs[ks % 3], wm, wn, fr, fq, acc);
  }
  const int b = m0 >> 7;
  float rsq[4][4] = {};
#pragma unroll
  for (int nj = 0; nj < 2; ++nj) {
    const int n = n0 + wn * 32 + nj * 16 + fr;
    const float sc = gam[n] * BN_SC, bi = bias[n], be = bet[n];
#pragma unroll
    for (int mi = 0; mi < 4; ++mi) {
      const int m = m0 + wm * 64 + mi * 16 + fq * 4;
      us4 pk;
#pragma unroll
      for (int r = 0; r < 4; ++r) {
        const float x = sc * (acc[mi][nj][r] + bi) + be;
        const u16 hb = f2bf(fmaxf(x, 0.f));
        O[(size_t)(m + r) * DD + n] = hb;
        pk[r] = hb;
        const float h = bf2f(hb);  // norms must match stored bf16 H
        rsq[mi][r] += h * h;
      }
      *(us4*)&HT[((size_t)b * DD + n) * LL + (m & 127)] = pk;
    }
  }
#pragma unroll
  for (int mi = 0; mi < 4; ++mi)
#pragma unroll
    for (int r = 0; r < 4; ++r) {
      float v = rsq[mi][r];
      v += __shfl_xor(v, 1, 64); v += __shfl_xor(v, 2, 64);
      v += __shfl_xor(v, 4, 64); v += __shfl_xor(v, 8, 64);
      rsq[mi][r] = v;
    }
  if (fr == 0) {
    const int p = blockIdx.y * 2 + wn;  // 8 partials per row
#pragma unroll
    for (int mi = 0; mi < 4; ++mi)
#pragma unroll
      for (int r = 0; r < 4; ++r)
        SQP[(size_t)p * MROWS + m0 + wm * 64 + mi * 16 + fq * 4 + r] = rsq[mi][r];
  }
}

// ------- fused att+attn per (batch, N-half, side): E in LDS, PV out ------
__global__ __launch_bounds__(256, 2)
void attf(const u16* __restrict__ H1, const u16* __restrict__ H2,
          const float* __restrict__ SQP1, const float* __restrict__ SQP2,
          const u16* __restrict__ HT1, const u16* __restrict__ HT2,
          u16* __restrict__ BETA, u16* __restrict__ ALPHA) {
  const int b = blockIdx.x, nh = blockIdx.y, side = blockIdx.z;
  __shared__ u16 Elds[128 * 128];  // 32KB swizzled (Ê or Ê^T per side)
  __shared__ float sqs[2][128], rowp[2][128], colp[2][128];
  const int t = threadIdx.x, lane = t & 63, w = t >> 6;
  const int wm = w >> 1, wn = w & 1;
  const int fr = lane & 15, fq = lane >> 4;
  const int r0 = b * LL;
  if (t < 128) {
    float s = 0.f;
#pragma unroll
    for (int p = 0; p < 8; ++p) s += SQP1[(size_t)p * MROWS + r0 + t];
    sqs[0][t] = s;
  } else {
    const int u = t - 128;
    float s = 0.f;
#pragma unroll
    for (int p = 0; p < 8; ++p) s += SQP2[(size_t)p * MROWS + r0 + u];
    sqs[1][u] = s;
  }
  // QK^T: full 128x128 E, no-LDS frag loads
  f4 acc[4][4] = {};
#pragma unroll
  for (int ks = 0; ks < 8; ++ks) {
    bfrag a[4], bv[4];
#pragma unroll
    for (int mi = 0; mi < 4; ++mi)
      a[mi] = gfrag(H1, DD, r0 + wm * 64 + mi * 16 + fr, ks * 32 + fq * 8);
#pragma unroll
    for (int nj = 0; nj < 4; ++nj)
      bv[nj] = gfrag(H2, DD, r0 + wn * 64 + nj * 16 + fr, ks * 32 + fq * 8);
#pragma unroll
    for (int mi = 0; mi < 4; ++mi)
#pragma unroll
      for (int nj = 0; nj < 4; ++nj) acc[mi][nj] = MFMA_B16(a[mi], bv[nj], acc[mi][nj]);
  }
  __syncthreads();  // sqs visible
  float rp[4][4] = {}, cp[4] = {};
#pragma unroll
  for (int nj = 0; nj < 4; ++nj) {
    const int n = wn * 64 + nj * 16 + fr;
    const float s2 = sqs[1][n];
#pragma unroll
    for (int mi = 0; mi < 4; ++mi) {
      const int m = wm * 64 + mi * 16 + fq * 4;
#pragma unroll
      for (int r = 0; r < 4; ++r) {
        const float d = sqs[0][m + r] + s2 - 2.f * acc[mi][nj][r];
        const float e = __expf(1.f / (1.f + d));
        acc[mi][nj][r] = e;
        rp[mi][r] += e;
        cp[nj] += e;
      }
    }
  }
#pragma unroll
  for (int mi = 0; mi < 4; ++mi)
#pragma unroll
    for (int r = 0; r < 4; ++r) {
      float v = rp[mi][r];
      v += __shfl_xor(v, 1, 64); v += __shfl_xor(v, 2, 64);
      v += __shfl_xor(v, 4, 64); v += __shfl_xor(v, 8, 64);
      rp[mi][r] = v;
    }
#pragma unroll
  for (int nj = 0; nj < 4; ++nj) {
    float v = cp[nj];
    v += __shfl_xor(v, 16, 64); v += __shfl_xor(v, 32, 64);
    cp[nj] = v;
  }
  if (fr == 0)
#pragma unroll
    for (int mi = 0; mi < 4; ++mi)
#pragma unroll
      for (int r = 0; r < 4; ++r)
        rowp[wn][wm * 64 + mi * 16 + fq * 4 + r] = rp[mi][r];
  if (fq == 0)
#pragma unroll
    for (int nj = 0; nj < 4; ++nj)
      colp[wm][wn * 64 + nj * 16 + fr] = cp[nj];
  __syncthreads();
  if (side == 0) {  // row-normalized Ê
#pragma unroll
    for (int nj = 0; nj < 4; ++nj) {
      const int n = wn * 64 + nj * 16 + fr;
#pragma unroll
      for (int mi = 0; mi < 4; ++mi) {
        const int m = wm * 64 + mi * 16 + fq * 4;
#pragma unroll
        for (int r = 0; r < 4; ++r) {
          const float riv = 1.f / (rowp[0][m + r] + rowp[1][m + r]);
          *(u16*)((char*)Elds + eswz(m + r, n * 2)) = f2bf(acc[mi][nj][r] * riv);
        }
      }
    }
  } else {  // col-normalized Ê^T
#pragma unroll
    for (int nj = 0; nj < 4; ++nj) {
      const int n = wn * 64 + nj * 16 + fr;
      const float civ = 1.f / (colp[0][n] + colp[1][n]);
#pragma unroll
      for (int mi = 0; mi < 4; ++mi) {
        const int m = wm * 64 + mi * 16 + fq * 4;
        us4 pk;
#pragma unroll
        for (int r = 0; r < 4; ++r) pk[r] = f2bf(acc[mi][nj][r] * civ);
        *(us4*)((char*)Elds + eswz(n, m * 2)) = pk;
      }
    }
  }
  __syncthreads();
  // PV: O = Ê @ H (B-frags from HT rows = H columns), this block's 128-col half
  const u16* HT = side ? HT1 : HT2;
  f4 pv[4][4] = {};
#pragma unroll
  for (int ks = 0; ks < 4; ++ks) {
    bfrag a[4], bv[4];
#pragma unroll
    for (int mi = 0; mi < 4; ++mi)
      a[mi] = ldsE(Elds, wm * 64 + mi * 16 + fr, ks * 64 + fq * 16);
#pragma unroll
    for (int nj = 0; nj < 4; ++nj)
      bv[nj] = gfrag(HT, LL, b * DD + nh * 128 + wn * 64 + nj * 16 + fr, ks * 32 + fq * 8);
#pragma unroll
    for (int mi = 0; mi < 4; ++mi)
#pragma unroll
      for (int nj = 0; nj < 4; ++nj) pv[mi][nj] = MFMA_B16(a[mi], bv[nj], pv[mi][nj]);
  }
  u16* O = side ? ALPHA : BETA;
#pragma unroll
  for (int nj = 0; nj < 4; ++nj) {
    const int n = nh * 128 + wn * 64 + nj * 16 + fr;
#pragma unroll
    for (int mi = 0; mi < 4; ++mi) {
      const int m = wm * 64 + mi * 16 + fq * 4;
#pragma unroll
      for (int r = 0; r < 4; ++r)
        O[(size_t)(r0 + m + r) * DD + n] = f2bf(pv[mi][nj][r]);
    }
  }
}

// --- vg n64 BK=64 swizzled, wait-then-issue counted pipeline -------------
__global__ __launch_bounds__(256, 2)
void mfma_vg(const u16* __restrict__ Hbf1, const u16* __restrict__ Hbf2,
             const u16* __restrict__ BETA, const u16* __restrict__ ALPHA,
             const u16* __restrict__ Wt2, const u16* __restrict__ Wtg,
             const float* __restrict__ b2, const float* __restrict__ g2,
             const float* __restrict__ be2, const float* __restrict__ bgv,
             u16* __restrict__ X0, u16* __restrict__ X1p, int dopool,
             u16* __restrict__ VPh, u16* __restrict__ VPl) {
  const int side = blockIdx.z;
  const u16* H = side ? Hbf2 : Hbf1;
  const u16* CC = side ? ALPHA : BETA;
  u16* X = side ? X1p : X0;
  const int m0 = blockIdx.x * 128, n0 = blockIdx.y * 64;
  __shared__ u16 As[2][128 * 64], B2s[2][64 * 64], Bgs[2][64 * 64];  // 64KB
  __shared__ float pmx[2][64], psm[2][64];
  const int t = threadIdx.x;
  const int lane = t & 63, w = t >> 6, wm = w >> 1, wn = w & 1;
  const int fr = lane & 15, fq = lane >> 4;
  f4 accv[4][2] = {}, accg[4][2] = {};
  stage128x64(H, DD, m0, 0, As[0], t);
  stage64x64(Wt2, 2 * DD, n0, 0, B2s[0], t);
  stage64x64(Wtg, DD, n0, 0, Bgs[0], t);
  for (int ks = 0; ks < 8; ++ks) {
    // stage(ks) has aged one full compute phase; stage(ks+1) not yet issued.
    asm volatile("s_waitcnt vmcnt(0)" ::: "memory");
    __builtin_amdgcn_sched_barrier(0);
    __builtin_amdgcn_s_barrier();
    // issue stage(ks+1) now; it flies during compute(ks).
    if (ks + 1 < 8) {
      const u16* Asrc = (ks + 1 < 4) ? H : CC;
      stage128x64(Asrc, DD, m0, ((ks + 1) & 3) * 64, As[(ks + 1) & 1], t);
      stage64x64(Wt2, 2 * DD, n0, (ks + 1) * 64, B2s[(ks + 1) & 1], t);
      if (ks + 1 < 4) stage64x64(Wtg, DD, n0, (ks + 1) * 64, Bgs[(ks + 1) & 1], t);
    }
    if (ks < 4)
      step2_k64(As[ks & 1], B2s[ks & 1], Bgs[ks & 1], wm, wn, fr, fq, accv, accg);
    else
      step_k64(As[ks & 1], B2s[ks & 1], wm, wn, fr, fq, accv);
  }
  float pmax[2] = {-1e30f, -1e30f}, psum[2] = {0.f, 0.f};
#pragma unroll
  for (int nj = 0; nj < 2; ++nj) {
    const int n = n0 + wn * 32 + nj * 16 + fr;
    const float sc = g2[n] * BN_SC, bi = b2[n], be = be2[n], bgn = bgv[n];
#pragma unroll
    for (int mi = 0; mi < 4; ++mi) {
      const int m = m0 + wm * 64 + mi * 16 + fq * 4;
#pragma unroll
      for (int r = 0; r < 4; ++r) {
        const float v = fmaxf(sc * (accv[mi][nj][r] + bi) + be, 0.f);
        const float g = 1.f / (1.f + __expf(-(accg[mi][nj][r] + bgn)));
        const float h = bf2f(H[(size_t)(m + r) * DD + n]);
        const u16 xb = f2bf(v * g + h * (1.f - g));
        X[(size_t)(m + r) * DD + n] = xb;
        if (dopool) {
          const float xv = bf2f(xb);
          pmax[nj] = fmaxf(pmax[nj], xv);
          psum[nj] += xv;
        }
      }
    }
  }
  if (dopool) {
#pragma unroll
    for (int nj = 0; nj < 2; ++nj) {
      float mx = pmax[nj], sm = psum[nj];
      mx = fmaxf(mx, __shfl_xor(mx, 16, 64)); sm += __shfl_xor(sm, 16, 64);
      mx = fmaxf(mx, __shfl_xor(mx, 32, 64)); sm += __shfl_xor(sm, 32, 64);
      if (fq == 0) {
        pmx[wm][wn * 32 + nj * 16 + fr] = mx;
        psm[wm][wn * 32 + nj * 16 + fr] = sm;
      }
    }
    __syncthreads();
    if (t < 64) {
      const float mx = fmaxf(pmx[0][t], pmx[1][t]);
      const float sm = psm[0][t] + psm[1][t];
      const int b = m0 >> 7;
      const int col = n0 + t;
      const u16 mh = f2bf(mx);
      VPh[(size_t)b * 1024 + side * 256 + col] = mh;
      VPl[(size_t)b * 1024 + side * 256 + col] = f2bf(mx - bf2f(mh));
      const u16 sh = f2bf(sm);
      VPh[(size_t)b * 1024 + (2 + side) * 256 + col] = sh;
      VPl[(size_t)b * 1024 + (2 + side) * 256 + col] = f2bf(sm - bf2f(sh));
    }
  }
}

// ---------------- MLP split-K no-LDS: PART[slice] = (Ah+Al) @ Wt-slice ---
__global__ __launch_bounds__(256, 2)
void mlp_sk(const u16* __restrict__ Ah, const u16* __restrict__ Al,
            const u16* __restrict__ Wt, float* __restrict__ PART) {
  const int n0 = blockIdx.x * 128;   // 8 N-blocks
  const int k0 = blockIdx.y * 128;   // 8 K-slices
  const int t = threadIdx.x, lane = t & 63, w = t >> 6;
  const int wm = w >> 1, wn = w & 1;
  const int fr = lane & 15, fq = lane >> 4;
  f4 acc[4][4] = {};
#pragma unroll
  for (int ks = 0; ks < 4; ++ks) {
    bfrag ah[4], al[4], bv[4];
#pragma unroll
    for (int mi = 0; mi < 4; ++mi) {
      ah[mi] = gfrag(Ah, 1024, wm * 64 + mi * 16 + fr, k0 + ks * 32 + fq * 8);
      al[mi] = gfrag(Al, 1024, wm * 64 + mi * 16 + fr, k0 + ks * 32 + fq * 8);
    }
#pragma unroll
    for (int nj = 0; nj < 4; ++nj)
      bv[nj] = gfrag(Wt, 1024, n0 + wn * 64 + nj * 16 + fr, k0 + ks * 32 + fq * 8);
#pragma unroll
    for (int mi = 0; mi < 4; ++mi)
#pragma unroll
      for (int nj = 0; nj < 4; ++nj) {
        acc[mi][nj] = MFMA_B16(ah[mi], bv[nj], acc[mi][nj]);
        acc[mi][nj] = MFMA_B16(al[mi], bv[nj], acc[mi][nj]);
      }
  }
#pragma unroll
  for (int nj = 0; nj < 4; ++nj) {
    const int n = n0 + wn * 64 + nj * 16 + fr;
#pragma unroll
    for (int mi = 0; mi < 4; ++mi) {
      const int m = wm * 64 + mi * 16 + fq * 4;
#pragma unroll
      for (int r = 0; r < 4; ++r)
        PART[((size_t)blockIdx.y * 128 + m + r) * 1024 + n] = acc[mi][nj][r];
    }
  }
}

// combine 8 partials + bias + relu -> hi/lo bf16 (first MLP)
__global__ __launch_bounds__(512)
void mlp_comb(const float* __restrict__ P, const float* __restrict__ bias,
              u16* __restrict__ Oh, u16* __restrict__ Ol) {
#pragma unroll
  for (int e = 0; e < 8; ++e) {
    const int idx = blockIdx.x * 4096 + e * 512 + threadIdx.x;
    const int col = idx & 1023;
    float s = bias[col];
#pragma unroll
    for (int p = 0; p < 8; ++p) s += P[(size_t)p * 131072 + idx];
    s = fmaxf(s, 0.f);
    const u16 h = f2bf(s);
    Oh[idx] = h;
    Ol[idx] = f2bf(s - bf2f(h));
  }
}

// combine 8 partials + bias + relu + final Wout dot -> logits (second MLP)
__global__ __launch_bounds__(512)
void mlp_comb_out(const float* __restrict__ P, const float* __restrict__ bias,
                  const float* __restrict__ Wout, const float* __restrict__ bout,
                  float* __restrict__ out) {
  __shared__ float red[4][8][3];
  const int t = threadIdx.x;
  float a[4][3] = {};
#pragma unroll
  for (int e = 0; e < 8; ++e) {
    const int idx = blockIdx.x * 4096 + e * 512 + t;
    const int col = idx & 1023;
    float s = bias[col];
#pragma unroll
    for (int p = 0; p < 8; ++p) s += P[(size_t)p * 131072 + idx];
    s = fmaxf(s, 0.f);
    const int lr = e >> 1;  // local row 0..3 (rows blk*4 .. blk*4+3)
    a[lr][0] = fmaf(s, Wout[col * 3 + 0], a[lr][0]);
    a[lr][1] = fmaf(s, Wout[col * 3 + 1], a[lr][1]);
    a[lr][2] = fmaf(s, Wout[col * 3 + 2], a[lr][2]);
  }
  const int lane = t & 63, w = t >> 6;
#pragma unroll
  for (int lr = 0; lr < 4; ++lr)
#pragma unroll
    for (int c = 0; c < 3; ++c) {
      float v = a[lr][c];
#pragma unroll
      for (int off = 32; off > 0; off >>= 1) v += __shfl_down(v, off, 64);
      if (lane == 0) red[lr][w][c] = v;
    }
  __syncthreads();
  if (t < 12) {
    const int lr = t / 3, c = t % 3;
    float s = bout[c];
#pragma unroll
    for (int w8 = 0; w8 < 8; ++w8) s += red[lr][w8][c];
    out[(blockIdx.x * 4 + lr) * 3 + c] = s;
  }
}

extern "C" void kernel_launch(void* const* d_in, const int* in_sizes, int n_in,
                              void* d_out, int out_size, void* d_ws, size_t ws_size,
                              hipStream_t stream) {
  (void)in_sizes; (void)n_in; (void)out_size; (void)ws_size;
  const float* embed = (const float*)d_in[0];
  const float* W1f   = (const float*)d_in[1];
  const float* W1r   = (const float*)d_in[2];
  const float* b1    = (const float*)d_in[3];
  const float* bn1g  = (const float*)d_in[4];
  const float* bn1b  = (const float*)d_in[5];
  const float* W2    = (const float*)d_in[6];
  const float* b2    = (const float*)d_in[7];
  const float* bn2g  = (const float*)d_in[8];
  const float* bn2b  = (const float*)d_in[9];
  const float* Wg    = (const float*)d_in[10];
  const float* bg    = (const float*)d_in[11];
  const float* Wf1   = (const float*)d_in[12];
  const float* bf1   = (const float*)d_in[13];
  const float* Wf2   = (const float*)d_in[14];
  const float* bf2   = (const float*)d_in[15];
  const float* Wout  = (const float*)d_in[16];
  const float* bout  = (const float*)d_in[17];
  const int* ids1    = (const int*)d_in[18];
  const int* ids2    = (const int*)d_in[19];

  char* wsp = (char*)d_ws;
  auto alloc = [&](size_t bytes) {
    char* p = wsp;
    wsp += (bytes + 255) & ~(size_t)255;
    return p;
  };
  u16* Hbf1  = (u16*)alloc((size_t)MROWS * DD * 2);
  u16* Hbf2  = (u16*)alloc((size_t)MROWS * DD * 2);
  u16* HT1   = (u16*)alloc((size_t)MROWS * DD * 2);
  u16* HT2   = (u16*)alloc((size_t)MROWS * DD * 2);
  u16* Xbf1  = (u16*)alloc((size_t)MROWS * 320 * 2);
  u16* Xbf2  = (u16*)alloc((size_t)MROWS * 320 * 2);
  u16* BETAb = (u16*)alloc((size_t)MROWS * DD * 2);
  u16* ALPHAb= (u16*)alloc((size_t)MROWS * DD * 2);
  float* SQP1= (float*)alloc((size_t)8 * MROWS * 4);
  float* SQP2= (float*)alloc((size_t)8 * MROWS * 4);
  u16* Wt1f  = (u16*)alloc((size_t)DD * 320 * 2);
  u16* Wt1r  = (u16*)alloc((size_t)9 * DD * DD * 2);
  u16* Wt2   = (u16*)alloc((size_t)10 * DD * 2 * DD * 2);
  u16* Wtg   = (u16*)alloc((size_t)10 * DD * DD * 2);
  u16* Wf1t  = (u16*)alloc((size_t)1024 * 1024 * 2);
  u16* Wf2t  = (u16*)alloc((size_t)1024 * 1024 * 2);
  u16* VPh   = (u16*)alloc((size_t)128 * 1024 * 2);
  u16* VPl   = (u16*)alloc((size_t)128 * 1024 * 2);
  u16* T1h   = (u16*)alloc((size_t)128 * 1024 * 2);
  u16* T1l   = (u16*)alloc((size_t)128 * 1024 * 2);
  float* PART1 = (float*)alloc((size_t)8 * 128 * 1024 * 4);
  float* PART2 = (float*)alloc((size_t)8 * 128 * 1024 * 4);

  k_prep<<<512, 256, 0, stream>>>(W1f, W1r, W2, Wg, Wf1, Wf2,
                                  Wt1f, Wt1r, Wt2, Wtg, Wf1t, Wf2t,
                                  embed, ids1, ids2, Xbf1, Xbf2, VPh, VPl);

  for (int i = 0; i < NLAYERS; ++i) {
    const u16* Wt1 = (i == 0) ? Wt1f : (Wt1r + (size_t)(i - 1) * DD * DD);
    const int K1 = (i == 0) ? 320 : DD;
    mfma_lbr<<<dim3(MROWS / 128, 4, 2), 256, 0, stream>>>(
        Xbf1, Xbf2, K1, K1, Wt1, b1 + i * DD, bn1g + i * DD, bn1b + i * DD,
        Hbf1, Hbf2, HT1, HT2, SQP1, SQP2);
    attf<<<dim3(NB, 2, 2), 256, 0, stream>>>(Hbf1, Hbf2, SQP1, SQP2, HT1, HT2,
                                             BETAb, ALPHAb);
    mfma_vg<<<dim3(MROWS / 128, 4, 2), 256, 0, stream>>>(
        Hbf1, Hbf2, BETAb, ALPHAb, Wt2 + (size_t)i * DD * 2 * DD,
        Wtg + (size_t)i * DD * DD, b2 + i * DD, bn2g + i * DD, bn2b + i * DD,
        bg + i * DD, Xbf1, Xbf2, (i == NLAYERS - 1) ? 1 : 0, VPh, VPl);
  }
  mlp_sk<<<dim3(8, 8), 256, 0, stream>>>(VPh, VPl, Wf1t, PART1);
  mlp_comb<<<32, 512, 0, stream>>>(PART1, bf1, T1h, T1l);
  mlp_sk<<<dim3(8, 8), 256, 0, stream>>>(T1h, T1l, Wf2t, PART2);
  mlp_comb_out<<<16, 512, 0, stream>>>(PART2, bf2, Wout, bout, (float*)d_out);
}